// Round 1
// 1389.659 us; speedup vs baseline: 1.0828x; 1.0828x over previous
//
#include <hip/hip_runtime.h>
#include <math.h>

#define N_SEQ 4096
#define KCH   16
#define DM    256
#define G4    1024
// padded-LDS pitch for the legacy post-round kernels
#define LP    40
#define EP    68   // epilogue scratch pitch in floats

typedef __attribute__((ext_vector_type(8))) short bf8;
typedef __attribute__((ext_vector_type(4))) float f4;

__device__ __forceinline__ float fast_rcp(float x) { return __builtin_amdgcn_rcpf(x); }
__device__ __forceinline__ float sigf(float x)   { return fast_rcp(1.f + __expf(-x)); }
__device__ __forceinline__ float tanh_f(float x) { return 1.f - 2.f * fast_rcp(1.f + __expf(2.f * x)); }

__device__ __forceinline__ float bf2f(unsigned short u) {
    return __uint_as_float(((unsigned)u) << 16);
}
__device__ __forceinline__ unsigned short f2bf(float f) {
    unsigned u = __float_as_uint(f);
    unsigned r = (u + 0x7fffu + ((u >> 16) & 1u)) >> 16;   // RNE
    return (unsigned short)r;
}
__device__ __forceinline__ unsigned pack2(float a, float b) {
    return (unsigned)f2bf(a) | ((unsigned)f2bf(b) << 16);
}

// async global->LDS, 16B per lane; LDS dest = wave-uniform base + lane*16
#define GLDS(gp, lp) __builtin_amdgcn_global_load_lds( \
    (const __attribute__((address_space(1))) void*)(gp), \
    (__attribute__((address_space(3))) void*)(lp), 16, 0, 0)

// ===========================================================================
// Pipelined MFMA pass: acc[4][4] += A[128,K]@B[128,K]^T over NSEG segments of
// K=256 each, bf16, rows dense.  Double-buffered LDS tiles (A0,B0,A1,B1 =
// 4x8KB = 32 KB) with counted-vmcnt prefetch: step t+1's 4 global_load_lds
// are issued BEFORE step t's compute, and only vmcnt(4) is waited at the
// barrier -- the prefetch stays in flight across it (T3+T4).  Never vmcnt(0)
// mid-loop.  lgkmcnt(0)+s_barrier at step end guarantees all waves' ds_reads
// retired before the buffer is overwritten two steps later.
// Layout identical to the proven pass_glk: XOR chunk swizzle on the global
// source (jl) and on the fragment reads (jq); LDS itself linear.
// ===========================================================================
template<int NSEG, int LDB>
__device__ __forceinline__ void pass_pipe(
    const unsigned short* const (&segA)[NSEG],
    const unsigned short* const (&segB)[NSEG],
    unsigned short* SM,                      // 16384 shorts = 32 KB
    f4 (&acc)[4][4], int wave, int wm, int wn, int jq, int fr)
{
    unsigned short* const la[2] = { SM + wave * 1024,        SM + 8192 + wave * 1024 };
    unsigned short* const lb[2] = { SM + 4096 + wave * 1024, SM + 12288 + wave * 1024 };
    constexpr int NS = NSEG * 8;

    // prologue: issue step 0 into buffer 0
    {
        const unsigned short* A_ = segA[0];
        const unsigned short* B_ = segB[0];
        GLDS(A_, la[0]);             GLDS(A_ + 16 * DM, la[0] + 512);
        GLDS(B_, lb[0]);             GLDS(B_ + 16 * LDB, lb[0] + 512);
    }
#pragma unroll
    for (int t = 0; t < NS; ++t) {
        if (t + 1 < NS) {
            // issue next step's loads into the other buffer (last read at
            // step t-1; all reads retired before that step's trailing barrier)
            const unsigned short* A_ = segA[(t + 1) >> 3] + ((t + 1) & 7) * 32;
            const unsigned short* B_ = segB[(t + 1) >> 3] + ((t + 1) & 7) * 32;
            const int nb = (t + 1) & 1;
            GLDS(A_, la[nb]);        GLDS(A_ + 16 * DM, la[nb] + 512);
            GLDS(B_, lb[nb]);        GLDS(B_ + 16 * LDB, lb[nb] + 512);
            // wait own step-t loads only; the 4 just-issued stay in flight
            asm volatile("s_waitcnt vmcnt(4)" ::: "memory");
        } else {
            asm volatile("s_waitcnt vmcnt(0)" ::: "memory");
        }
        __builtin_amdgcn_s_barrier();          // all waves' step-t data landed

        const unsigned short* Ab = SM + (t & 1) * 8192;
        const unsigned short* Bb = Ab + 4096;
        bf8 af[4], bb[4];
#pragma unroll
        for (int i = 0; i < 4; ++i)
            af[i] = *(const bf8*)(Ab + (wm + i * 16 + fr) * 32 + jq);
#pragma unroll
        for (int j = 0; j < 4; ++j)
            bb[j] = *(const bf8*)(Bb + (wn + j * 16 + fr) * 32 + jq);
#pragma unroll
        for (int i = 0; i < 4; ++i)
#pragma unroll
            for (int j = 0; j < 4; ++j)
                acc[i][j] = __builtin_amdgcn_mfma_f32_16x16x32_bf16(
                    af[i], bb[j], acc[i][j], 0, 0, 0);

        // all this wave's ds_reads retired -> after the barrier every wave
        // may safely overwrite buffer t&1 (happens at iteration t+1's issue)
        asm volatile("s_waitcnt lgkmcnt(0)" ::: "memory");
        __builtin_amdgcn_s_barrier();
    }
}

// ===========================================================================
// Legacy padded-LDS passes (post-round one-shot kernels; proven correct)
// ===========================================================================
template<int KLEN>
__device__ __forceinline__ void pass_bf(
    const unsigned short* __restrict__ aRow,
    const unsigned short* __restrict__ bRow,
    unsigned short* Asm, unsigned short* Bsm, f4 (&acc)[4][4])
{
    const int tid  = threadIdx.x;
    const int kh   = (tid & 1) * 16;
    const int srow = tid >> 1;
    const int lane = tid & 63, wave = tid >> 6;
    const int wm = (wave >> 1) * 64, wn = (wave & 1) * 64;
    const int fr = lane & 15, fk = (lane >> 4) * 8;
    unsigned short* da = Asm + srow * LP + kh;
    unsigned short* db = Bsm + srow * LP + kh;

    for (int k0 = 0; k0 < KLEN; k0 += 32) {
        __syncthreads();
        *(int4*)(da)     = *(const int4*)(aRow + k0 + kh);
        *(int4*)(da + 8) = *(const int4*)(aRow + k0 + kh + 8);
        *(int4*)(db)     = *(const int4*)(bRow + k0 + kh);
        *(int4*)(db + 8) = *(const int4*)(bRow + k0 + kh + 8);
        __syncthreads();
        bf8 af[4], bb[4];
#pragma unroll
        for (int i = 0; i < 4; ++i)
            af[i] = *(const bf8*)(Asm + (wm + i * 16 + fr) * LP + fk);
#pragma unroll
        for (int j = 0; j < 4; ++j)
            bb[j] = *(const bf8*)(Bsm + (wn + j * 16 + fr) * LP + fk);
#pragma unroll
        for (int i = 0; i < 4; ++i)
#pragma unroll
            for (int j = 0; j < 4; ++j)
                acc[i][j] = __builtin_amdgcn_mfma_f32_16x16x32_bf16(
                    af[i], bb[j], acc[i][j], 0, 0, 0);
    }
}

template<int KLEN>
__device__ __forceinline__ void pass_f32(
    const float* __restrict__ aRow,
    const unsigned short* __restrict__ bRow,
    unsigned short* Asm, unsigned short* Bsm, f4 (&acc)[4][4])
{
    const int tid  = threadIdx.x;
    const int kh   = (tid & 1) * 16;
    const int srow = tid >> 1;
    const int lane = tid & 63, wave = tid >> 6;
    const int wm = (wave >> 1) * 64, wn = (wave & 1) * 64;
    const int fr = lane & 15, fk = (lane >> 4) * 8;
    unsigned short* da = Asm + srow * LP + kh;
    unsigned short* db = Bsm + srow * LP + kh;

    for (int k0 = 0; k0 < KLEN; k0 += 32) {
        __syncthreads();
        {
            const float* s = aRow + k0 + kh;
            float4 v0 = *(const float4*)(s);
            float4 v1 = *(const float4*)(s + 4);
            float4 v2 = *(const float4*)(s + 8);
            float4 v3 = *(const float4*)(s + 12);
            *(int4*)(da)     = make_int4(pack2(v0.x, v0.y), pack2(v0.z, v0.w),
                                         pack2(v1.x, v1.y), pack2(v1.z, v1.w));
            *(int4*)(da + 8) = make_int4(pack2(v2.x, v2.y), pack2(v2.z, v2.w),
                                         pack2(v3.x, v3.y), pack2(v3.z, v3.w));
        }
        *(int4*)(db)     = *(const int4*)(bRow + k0 + kh);
        *(int4*)(db + 8) = *(const int4*)(bRow + k0 + kh + 8);
        __syncthreads();
        bf8 af[4], bb[4];
#pragma unroll
        for (int i = 0; i < 4; ++i)
            af[i] = *(const bf8*)(Asm + (wm + i * 16 + fr) * LP + fk);
#pragma unroll
        for (int j = 0; j < 4; ++j)
            bb[j] = *(const bf8*)(Bsm + (wn + j * 16 + fr) * LP + fk);
#pragma unroll
        for (int i = 0; i < 4; ++i)
#pragma unroll
            for (int j = 0; j < 4; ++j)
                acc[i][j] = __builtin_amdgcn_mfma_f32_16x16x32_bf16(
                    af[i], bb[j], acc[i][j], 0, 0, 0);
    }
}

// --------------------------- setup kernels ----------------------------------

__global__ __launch_bounds__(256) void k_lastidx(
    const int* __restrict__ indice, int* __restrict__ last_idx)
{
    const int n = blockIdx.x * 256 + threadIdx.x;
    if (n >= N_SEQ) return;
    int len = 0;
#pragma unroll
    for (int k = 0; k < KCH; ++k) len += (indice[n * KCH + k] != -1);
    last_idx[n] = indice[n * KCH + (len - 1)];
}

__global__ __launch_bounds__(1024) void k_hh0_bsum2(
    const float* __restrict__ bih, const float* __restrict__ bhh,
    const float* __restrict__ h0, const float* __restrict__ Whh,
    float* __restrict__ bsum2)
{
    const int jz = blockIdx.x, j = jz + 1;
    const int g = threadIdx.x;
    const int jd = j * 2 + 1;
    const float* wrow = Whh + ((size_t)jd * G4 + g) * DM;
    float s = bih[jd * G4 + g] + bhh[jd * G4 + g];
    for (int h = 0; h < DM; ++h) s = fmaf(h0[j * DM + h], wrow[h], s);
    const int c = (g & 255) * 4 + (g >> 8);
    bsum2[jz * G4 + c] = s;
}

__global__ __launch_bounds__(256) void k_init_states(
    const float* __restrict__ h0, const float* __restrict__ c0,
    unsigned short* __restrict__ hA, float* __restrict__ c_state)
{
    const int row = blockIdx.x;
    const int s = row >> 12;
    const int tree = (s < 4) ? s : 0;
    const int d = threadIdx.x;
    hA[(size_t)row * DM + d]      = f2bf(h0[tree * DM + d]);
    c_state[(size_t)row * DM + d] = c0[tree * DM + d];
}

__global__ __launch_bounds__(256) void k_zero4(float4* __restrict__ p)
{
    p[(size_t)blockIdx.x * 256 + threadIdx.x] = make_float4(0.f, 0.f, 0.f, 0.f);
}

__global__ __launch_bounds__(256) void k_prep_wcat(
    const float* __restrict__ Wih, const float* __restrict__ Whh,
    const float* __restrict__ bih, const float* __restrict__ bhh,
    unsigned short* __restrict__ wcat, float* __restrict__ bsumr)
{
    const int c = blockIdx.x, s = blockIdx.y;
    const int wsel = (s < 4) ? s * 2 : 1;
    const int d = c >> 2, g = c & 3;
    const size_t srcrow = ((size_t)wsel * G4 + g * DM + d) * DM;
    unsigned short* dst = wcat + ((size_t)s * G4 + c) * 512;
    const int t = threadIdx.x;
    dst[t]       = f2bf(Wih[srcrow + t]);
    dst[256 + t] = f2bf(Whh[srcrow + t]);
    if (t == 0)
        bsumr[s * G4 + c] = bih[wsel * G4 + g * DM + d] + bhh[wsel * G4 + g * DM + d];
}

__global__ __launch_bounds__(256) void k_prep_wcat2(
    const float* __restrict__ Wih, unsigned short* __restrict__ wcat2)
{
    const int c = blockIdx.x, jz = blockIdx.y, j = jz + 1;
    const int d = c >> 2, g = c & 3;
    const size_t srcrow = ((size_t)(j * 2 + 1) * G4 + g * DM + d) * DM;
    wcat2[((size_t)jz * G4 + c) * 256 + threadIdx.x] = f2bf(Wih[srcrow + threadIdx.x]);
}

__global__ __launch_bounds__(256) void k_prep_fcb(
    const float* __restrict__ fc, unsigned short* __restrict__ fcb)
{
    const int dout = blockIdx.x, z = blockIdx.y, t = threadIdx.x;
    fcb[((size_t)z * DM + dout) * DM + t] = f2bf(fc[(size_t)dout * 512 + z * DM + t]);
}

__global__ __launch_bounds__(256) void k_prep_fcb2(
    const float* __restrict__ fc, unsigned short* __restrict__ fcb2)
{
    const int dout = blockIdx.x, jz = blockIdx.y, j = jz + 1, t = threadIdx.x;
    const float* src = fc + ((size_t)j * DM + dout) * 512;
    unsigned short* dst = fcb2 + ((size_t)jz * DM + dout) * 512;
    dst[t]       = f2bf(src[t]);
    dst[t + 256] = f2bf(src[t + 256]);
}

__global__ __launch_bounds__(256) void k_prep_wwb(
    const float* __restrict__ W_w, unsigned short* __restrict__ wwb)
{
    const size_t i = (size_t)blockIdx.x * 256 + threadIdx.x;
    wwb[i] = f2bf(W_w[i]);
}

__device__ __forceinline__ void gather_slice(
    const float* __restrict__ h_tensor, const int* __restrict__ indice,
    unsigned short* __restrict__ xbuf, int zz, int kk, int blk)
{
    const int row = blk * 64 + (threadIdx.x >> 2);
    const int cb  = (threadIdx.x & 3) * 64;
    int idx = indice[row * KCH + kk]; if (idx < 0) idx = 0;
    const float* src = h_tensor + (size_t)idx * DM + cb;
    unsigned short* dst = xbuf + ((size_t)zz * N_SEQ + row) * DM + cb;
#pragma unroll
    for (int c = 0; c < 64; c += 4) {
        float4 v = *(const float4*)(src + c);
        *(uint2*)(dst + c) = make_uint2(pack2(v.x, v.y), pack2(v.z, v.w));
    }
}

__global__ __launch_bounds__(256) void k_gather_x0(
    const float* __restrict__ h_tensor, const int* __restrict__ indice,
    unsigned short* __restrict__ xbuf)
{
    const int slice = blockIdx.x >> 6, blk = blockIdx.x & 63;
    gather_slice(h_tensor, indice, xbuf, slice, slice ? (KCH - 1) : 0, blk);
}

// --------------------------- merged scan round ------------------------------
// grid (8, 32, 6):
//   bz<5 : scan for stream s=bz (XCD-swizzled: bn=by&7, bm=(by>>3)*8+bx so all
//          8 bn-siblings of one (bm,s) share id%8 -> same XCD -> A L2-local)
//   bz=5 : id5<128 -> acc_fc for round r-1 (y ping-pong);
//          id5>=128 -> gather xbuf slices for round r+1 (x ping-pong)
__global__ __launch_bounds__(256) void k_scan_merged(
    const unsigned short* __restrict__ xb_cur, unsigned short* __restrict__ xb_nxt,
    const unsigned short* __restrict__ yb_prev, unsigned short* __restrict__ yb_cur,
    const int* __restrict__ indice, const float* __restrict__ h_tensor,
    const unsigned short* __restrict__ h_in, unsigned short* __restrict__ h_out,
    float* __restrict__ c_state,
    const unsigned short* __restrict__ wcat, const float* __restrict__ bsumr,
    const unsigned short* __restrict__ fcb, unsigned short* __restrict__ ys0,
    int r)
{
    __shared__ __align__(16) unsigned short SMEM[16384];   // 32,768 B (A0,B0,A1,B1)

    const int tid  = threadIdx.x;
    const int lane = tid & 63, wave = tid >> 6;
    const int wm = (wave >> 1) * 64, wn = (wave & 1) * 64;
    const int fr = lane & 15;
    const int jq = ((lane >> 4) ^ ((fr >> 1) & 3)) * 8;        // frag-read swizzle
    const int lr = wave * 32 + (lane >> 2);                    // staging row
    const int jl = ((lane & 3) ^ ((lane >> 3) & 3)) * 8;       // staging swizzle

    const int bz = blockIdx.z;

    if (bz == 5) {
        const int id5 = blockIdx.x + 8 * blockIdx.y;
        if (id5 >= 128) {                 // gather role: xbuf for round r+1
            const int rr = r + 1;
            if (rr >= KCH) return;
            const int g = id5 - 128;
            const int zz = g >> 6;
            gather_slice(h_tensor, indice, xb_nxt, zz,
                         zz ? (KCH - 1 - rr) : rr, g & 63);
            return;
        }
        if (r == 0) return;               // acc role: fc-accumulate round r-1
        const int rp = r - 1;
        const int z = id5 >> 6;
        const int kslice = z ? (KCH - 1 - rp) : rp;
        const int row0 = (id5 & 31) * 128;
        const int c0 = ((id5 >> 5) & 1) * 128;

        const unsigned short* ay0 = yb_prev + ((size_t)z * N_SEQ + row0 + lr) * DM + jl;
        const unsigned short* bf0 = fcb + ((size_t)z * DM + c0 + lr) * DM + jl;

        f4 acc[4][4];
#pragma unroll
        for (int i = 0; i < 4; ++i)
#pragma unroll
            for (int j = 0; j < 4; ++j) acc[i][j] = (f4)(0.f);
        {
            const unsigned short* const segA[1] = { ay0 };
            const unsigned short* const segB[1] = { bf0 };
            pass_pipe<1, 256>(segA, segB, SMEM, acc, wave, wm, wn, jq, fr);
        }

#pragma unroll
        for (int i = 0; i < 4; ++i)
#pragma unroll
            for (int j = 0; j < 4; ++j) {
                const int col = c0 + wn + j * 16 + fr;
#pragma unroll
                for (int reg = 0; reg < 4; ++reg) {
                    const int rowg = row0 + wm + i * 16 + (lane >> 4) * 4 + reg;
                    const size_t ix = ((size_t)rowg * KCH + kslice) * DM + col;
                    ys0[ix] = f2bf(bf2f(ys0[ix]) + acc[i][j][reg]);
                }
            }
        return;
    }

    // ---- scan role ----
    const int s = bz;
    const int k = (s < 4) ? r : (KCH - 1 - r);
    const int z = (s < 4) ? 0 : 1;
    const int bn = blockIdx.y & 7;
    const int bm = (blockIdx.y >> 3) * 8 + blockIdx.x;
    const int row0 = bm * 128, c0 = bn * 128;

    const unsigned short* xz = xb_cur + (size_t)z * N_SEQ * DM;
    const unsigned short* hs_in = h_in + (size_t)s * N_SEQ * DM;
    const unsigned short* ax0 = xz + (size_t)(row0 + lr) * DM + jl;
    const unsigned short* ah0 = hs_in + (size_t)(row0 + lr) * DM + jl;
    const unsigned short* bw0 = wcat + ((size_t)s * G4 + c0 + lr) * 512 + jl;

    f4 acc[4][4];
#pragma unroll
    for (int i = 0; i < 4; ++i)
#pragma unroll
        for (int j = 0; j < 4; ++j) acc[i][j] = (f4)(0.f);

    {
        // one continuous 16-step pipeline across the x-pass and h-pass
        const unsigned short* const segA[2] = { ax0, ah0 };
        const unsigned short* const segB[2] = { bw0, bw0 + 256 };
        pass_pipe<2, 512>(segA, segB, SMEM, acc, wave, wm, wn, jq, fr);
    }

    // ---- fused LSTM epilogue (round-5 proven) ----
    float* sc = (float*)SMEM + wave * (16 * EP);
    __syncthreads();
#pragma unroll
    for (int i = 0; i < 4; ++i) {
#pragma unroll
        for (int j = 0; j < 4; ++j) {
            const int colL = j * 16 + fr;
            const int rbase = (lane >> 4) * 4;
#pragma unroll
            for (int reg = 0; reg < 4; ++reg)
                sc[(rbase + reg) * EP + colL] = acc[i][j][reg];
        }
        __syncthreads();
        const int rowg = row0 + wm + i * 16 + fr;
        const bool m = (indice[rowg * KCH + k] != -1);
#pragma unroll
        for (int q = 0; q < 4; ++q) {
            const int dL = (lane >> 4) + q * 4;
            const f4 gv = *(const f4*)(sc + fr * EP + dL * 4);
            const f4 bb = *(const f4*)(bsumr + s * G4 + c0 + wn + dL * 4);
            const int d = ((c0 + wn) >> 2) + dL;
            const float ii = sigf(gv.x + bb.x);
            const float ff = sigf(gv.y + bb.y);
            const float uu = tanh_f(gv.z + bb.z);
            const float oo = sigf(gv.w + bb.w);
            const size_t cix = ((size_t)s * N_SEQ + rowg) * DM + d;
            const float c_old = c_state[cix];
            const float cn = ff * c_old + ii * uu;
            const float cw = m ? cn : c_old;
            c_state[cix] = cw;
            const float hn = oo * tanh_f(cn);
            const unsigned short hv = m ? f2bf(hn) : hs_in[(size_t)rowg * DM + d];
            h_out[cix] = hv;
            if (s == 0)
                yb_cur[(size_t)rowg * DM + d] = m ? f2bf(hn) : (unsigned short)0;
            else if (s == 4)
                yb_cur[(size_t)(N_SEQ + rowg) * DM + d] = m ? f2bf(hn) : (unsigned short)0;
        }
        __syncthreads();
    }
}

// tail: acc_fc for r=15.  grid (2, 32, 2)
__global__ __launch_bounds__(256) void k_acc_tail(
    const unsigned short* __restrict__ ybuf, const unsigned short* __restrict__ fcb,
    unsigned short* __restrict__ ys0)
{
    __shared__ __align__(16) unsigned short SMEM[16384];
    const int tid = threadIdx.x;
    const int lane = tid & 63, wave = tid >> 6;
    const int wm = (wave >> 1) * 64, wn = (wave & 1) * 64;
    const int fr = lane & 15;
    const int jq = ((lane >> 4) ^ ((fr >> 1) & 3)) * 8;
    const int lr = wave * 32 + (lane >> 2);
    const int jl = ((lane & 3) ^ ((lane >> 3) & 3)) * 8;

    const int z = blockIdx.z;
    const int kslice = z ? 0 : (KCH - 1);
    const int row0 = blockIdx.y * 128, c0 = blockIdx.x * 128;

    const unsigned short* ay0 = ybuf + ((size_t)z * N_SEQ + row0 + lr) * DM + jl;
    const unsigned short* bf0 = fcb + ((size_t)z * DM + c0 + lr) * DM + jl;

    f4 acc[4][4];
#pragma unroll
    for (int i = 0; i < 4; ++i)
#pragma unroll
        for (int j = 0; j < 4; ++j) acc[i][j] = (f4)(0.f);
    {
        const unsigned short* const segA[1] = { ay0 };
        const unsigned short* const segB[1] = { bf0 };
        pass_pipe<1, 256>(segA, segB, SMEM, acc, wave, wm, wn, jq, fr);
    }

#pragma unroll
    for (int i = 0; i < 4; ++i)
#pragma unroll
        for (int j = 0; j < 4; ++j) {
            const int col = c0 + wn + j * 16 + fr;
#pragma unroll
            for (int reg = 0; reg < 4; ++reg) {
                const int rowg = row0 + wm + i * 16 + (lane >> 4) * 4 + reg;
                const size_t ix = ((size_t)rowg * KCH + kslice) * DM + col;
                ys0[ix] = f2bf(bf2f(ys0[ix]) + acc[i][j][reg]);
            }
        }
}

// --------------------------- post-round kernels -----------------------------

__global__ __launch_bounds__(256) void k_bwd_mfma(
    const float* __restrict__ h_tensor, const int* __restrict__ last_idx,
    const unsigned short* __restrict__ wcat2, const float* __restrict__ bsum2,
    const float* __restrict__ c0, unsigned short* __restrict__ yb_last)
{
    __shared__ __align__(16) unsigned short SMEM[2 * 128 * LP];
    const int jz = blockIdx.z, j = jz + 1;
    const int row0 = blockIdx.y * 128, c0t = blockIdx.x * 128;
    const int tid = threadIdx.x;
    const int srow = tid >> 1;

    const float* aF = h_tensor + (size_t)last_idx[row0 + srow] * DM;
    const unsigned short* bR = wcat2 + ((size_t)jz * G4 + c0t + srow) * 256;

    f4 acc[4][4];
#pragma unroll
    for (int i = 0; i < 4; ++i)
#pragma unroll
        for (int jj = 0; jj < 4; ++jj) acc[i][jj] = (f4)(0.f);

    pass_f32<256>(aF, bR, SMEM, SMEM + 128 * LP, acc);

    const int lane = tid & 63, wave = tid >> 6;
    const int wm = (wave >> 1) * 64, wn = (wave & 1) * 64;
    float* sc = (float*)SMEM + wave * (16 * EP);

    __syncthreads();
#pragma unroll
    for (int i = 0; i < 4; ++i) {
#pragma unroll
        for (int jj = 0; jj < 4; ++jj) {
            const int colL = jj * 16 + (lane & 15);
            const int rbase = (lane >> 4) * 4;
#pragma unroll
            for (int reg = 0; reg < 4; ++reg)
                sc[(rbase + reg) * EP + colL] = acc[i][jj][reg];
        }
        __syncthreads();
        const int rowg = row0 + wm + i * 16 + (lane & 15);
#pragma unroll
        for (int q = 0; q < 4; ++q) {
            const int dL = (lane >> 4) + q * 4;
            const f4 gv = *(const f4*)(sc + (lane & 15) * EP + dL * 4);
            const f4 bb = *(const f4*)(bsum2 + jz * G4 + c0t + wn + dL * 4);
            const int d = ((c0t + wn) >> 2) + dL;
            const float ii = sigf(gv.x + bb.x);
            const float ff = sigf(gv.y + bb.y);
            const float uu = tanh_f(gv.z + bb.z);
            const float oo = sigf(gv.w + bb.w);
            const float cn = ff * c0[j * DM + d] + ii * uu;
            yb_last[((size_t)jz * N_SEQ + rowg) * DM + d] = f2bf(oo * tanh_f(cn));
        }
        __syncthreads();
    }
}

__global__ __launch_bounds__(256) void k_wx_mfma(
    const float* __restrict__ x, const unsigned short* __restrict__ wwb,
    const float* __restrict__ W_b, unsigned short* __restrict__ Wx)
{
    __shared__ __align__(16) unsigned short SMEM[2 * 128 * LP];
    const int row0 = blockIdx.y * 128, c0 = blockIdx.x * 128;
    const int tid = threadIdx.x;
    const int srow = tid >> 1;

    const float* aF = x + (size_t)(row0 + srow) * DM;
    const unsigned short* bR = wwb + (size_t)(c0 + srow) * DM;

    f4 acc[4][4];
#pragma unroll
    for (int i = 0; i < 4; ++i)
#pragma unroll
        for (int j = 0; j < 4; ++j) acc[i][j] = (f4)(0.f);

    pass_f32<256>(aF, bR, SMEM, SMEM + 128 * LP, acc);

    const int lane = tid & 63, wave = tid >> 6;
    const int wm = (wave >> 1) * 64, wn = (wave & 1) * 64;
#pragma unroll
    for (int i = 0; i < 4; ++i)
#pragma unroll
        for (int j = 0; j < 4; ++j) {
            const int col = c0 + wn + j * 16 + (lane & 15);
            const float bv = W_b[col];
#pragma unroll
            for (int reg = 0; reg < 4; ++reg) {
                const int rowg = row0 + wm + i * 16 + (lane >> 4) * 4 + reg;
                Wx[(size_t)rowg * G4 + col] = f2bf(acc[i][j][reg] + bv);
            }
        }
}

__global__ __launch_bounds__(256) void k_fc_last_mfma(
    const unsigned short* __restrict__ h_final, const unsigned short* __restrict__ yb_last,
    const unsigned short* __restrict__ fcb2, unsigned short* __restrict__ ys_last)
{
    __shared__ __align__(16) unsigned short SMEM[2 * 128 * LP];
    const int jz = blockIdx.z;
    const int row0 = blockIdx.y * 128, c0 = blockIdx.x * 128;
    const int tid = threadIdx.x;
    const int srow = tid >> 1;

    const unsigned short* aH1 = h_final + ((size_t)(1 + jz) * N_SEQ + row0 + srow) * DM;
    const unsigned short* aH2 = yb_last + ((size_t)jz * N_SEQ + row0 + srow) * DM;
    const unsigned short* bR  = fcb2 + ((size_t)jz * DM + c0 + srow) * 512;

    f4 acc[4][4];
#pragma unroll
    for (int i = 0; i < 4; ++i)
#pragma unroll
        for (int j = 0; j < 4; ++j) acc[i][j] = (f4)(0.f);

    pass_bf<256>(aH1, bR, SMEM, SMEM + 128 * LP, acc);
    pass_bf<256>(aH2, bR + 256, SMEM, SMEM + 128 * LP, acc);

    const int lane = tid & 63, wave = tid >> 6;
    const int wm = (wave >> 1) * 64, wn = (wave & 1) * 64;
#pragma unroll
    for (int i = 0; i < 4; ++i)
#pragma unroll
        for (int j = 0; j < 4; ++j) {
            const int col = c0 + wn + j * 16 + (lane & 15);
#pragma unroll
            for (int reg = 0; reg < 4; ++reg) {
                const int rowg = row0 + wm + i * 16 + (lane >> 4) * 4 + reg;
                ys_last[((size_t)jz * N_SEQ + rowg) * DM + col] = f2bf(acc[i][j][reg]);
            }
        }
}

__global__ __launch_bounds__(256) void k_final(
    const unsigned short* __restrict__ Wx, const unsigned short* __restrict__ ys0,
    const unsigned short* __restrict__ ys_last, const float* __restrict__ c_tensor,
    const int* __restrict__ indice, float* __restrict__ out)
{
    const int n = blockIdx.x, d = threadIdx.x;
    const float Wf = bf2f(Wx[(size_t)n * G4 + d]);
    const float Wi = bf2f(Wx[(size_t)n * G4 + DM + d]);
    const float Wu = bf2f(Wx[(size_t)n * G4 + 2 * DM + d]);
    const float Wo = bf2f(Wx[(size_t)n * G4 + 3 * DM + d]);
    float bf = 0.f;
#pragma unroll
    for (int k = 0; k < KCH; ++k) {
        const int id = indice[n * KCH + k];
        if (id >= 0)
            bf += sigf(Wf + bf2f(ys0[((size_t)n * KCH + k) * DM + d])) *
                  c_tensor[(size_t)id * DM + d];
    }
    const float bi = sigf(bf2f(ys_last[((size_t)0 * N_SEQ + n) * DM + d]) + Wi);
    const float bu = tanh_f(bf2f(ys_last[((size_t)1 * N_SEQ + n) * DM + d]) + Wu);
    const float bo = sigf(bf2f(ys_last[((size_t)2 * N_SEQ + n) * DM + d]) + Wo);
    const float nc = bi * bu + bf;
    const float nh = bo * tanh_f(nc);
    out[(size_t)n * DM + d] = nh;
    out[(size_t)N_SEQ * DM + (size_t)n * DM + d] = nc;
}

// --------------------------- launcher ---------------------------------------
extern "C" void kernel_launch(void* const* d_in, const int* in_sizes, int n_in,
                              void* d_out, int out_size, void* d_ws, size_t ws_size,
                              hipStream_t stream)
{
    const float* x        = (const float*)d_in[0];
    const float* h_tensor = (const float*)d_in[1];
    const float* c_tensor = (const float*)d_in[2];
    const int*   indice   = (const int*)d_in[3];
    const float* W_w      = (const float*)d_in[4];
    const float* W_b      = (const float*)d_in[5];
    const float* h0       = (const float*)d_in[6];
    const float* c0       = (const float*)d_in[7];
    const float* Wih      = (const float*)d_in[8];
    const float* Whh      = (const float*)d_in[9];
    const float* bih      = (const float*)d_in[10];
    const float* bhh      = (const float*)d_in[11];
    const float* fc       = (const float*)d_in[12];
    float* out = (float*)d_out;

    // ---- workspace layout; need = 97,816,576 B (< proven 100,728,832) ----
    char* base = (char*)d_ws;
    float*          c_state  = (float*)(base + 0);                   // 20,971,520
    int*            last_idx = (int*)  (base + 20971520);            //     16,384
    float*          bsumr    = (float*)(base + 20987904);            //     20,480
    unsigned short* hA       = (unsigned short*)(base + 21008384);   // 10,485,760
    unsigned short* hB       = (unsigned short*)(base + 31494144);   // 10,485,760
    unsigned short* ys0      = (unsigned short*)(base + 41979904);   // 33,554,432
    unsigned short* ybufA    = (unsigned short*)(base + 75534336);   //  4,194,304
    unsigned short* ybufB    = (unsigned short*)(base + 79728640);   //  4,194,304
    unsigned short* xbufA    = (unsigned short*)(base + 83922944);   //  4,194,304
    unsigned short* fcb      = (unsigned short*)(base + 88117248);   //    262,144
    unsigned short* postbuf  = (unsigned short*)(base + 88379392);   //  4,194,304
    unsigned short* wcat     = (unsigned short*)(base + 92573696);   //  5,242,880
    const size_t need = 97816576;
    if (ws_size < need) return;   // diagnostic: zero-output absmax fail

    // aliases (disjoint lifetimes):
    unsigned short* xbufB   = postbuf;               // rounds only
    unsigned short* wcat2   = postbuf;               // post (1,572,864 B)
    unsigned short* fcb2    = postbuf + 786432;      // post (786,432 B)
    unsigned short* wwb     = postbuf + 1179648;     // post (524,288 B)
    float*          bsum2   = (float*)(postbuf + 1441792);  // post (12,288 B)
    unsigned short* yb_last = ybufA;                 // post (6.29 MB spans ybufA+B)
    unsigned short* ys_last = hB;                    // post (final h in hA)
    unsigned short* WxBuf   = hA;                    // post-fc_last (hA dead)

    k_lastidx<<<16, 256, 0, stream>>>(indice, last_idx);
    k_init_states<<<5 * N_SEQ, 256, 0, stream>>>(h0, c0, hA, c_state);
    k_zero4<<<8192, 256, 0, stream>>>((float4*)ys0);
    k_prep_wcat<<<dim3(G4, 5), 256, 0, stream>>>(Wih, Whh, bih, bhh, wcat, bsumr);
    k_prep_fcb<<<dim3(DM, 2), 256, 0, stream>>>(fc, fcb);
    k_gather_x0<<<128, 256, 0, stream>>>(h_tensor, indice, xbufA);

    for (int r = 0; r < KCH; ++r) {
        const unsigned short* xb_cur = (r & 1) ? xbufB : xbufA;
        unsigned short* xb_nxt       = (r & 1) ? xbufA : xbufB;
        const unsigned short* yb_prev = (r & 1) ? ybufA : ybufB;
        unsigned short* yb_cur        = (r & 1) ? ybufB : ybufA;
        const unsigned short* h_in = (r & 1) ? hB : hA;
        unsigned short* h_out      = (r & 1) ? hA : hB;
        k_scan_merged<<<dim3(8, 32, 6), 256, 0, stream>>>(
            xb_cur, xb_nxt, yb_prev, yb_cur, indice, h_tensor,
            h_in, h_out, c_state, wcat, bsumr, fcb, ys0, r);
    }
    // r=15 odd -> final h in hA; y_cur(r=15) in ybufB.

    k_acc_tail<<<dim3(2, 32, 2), 256, 0, stream>>>(ybufB, fcb, ys0);

    // post preps into postbuf (xbufB dead)
    k_prep_wcat2<<<dim3(G4, 3), 256, 0, stream>>>(Wih, wcat2);
    k_hh0_bsum2<<<3, 1024, 0, stream>>>(bih, bhh, h0, Whh, bsum2);
    k_prep_fcb2<<<dim3(DM, 3), 256, 0, stream>>>(fc, fcb2);
    k_prep_wwb<<<1024, 256, 0, stream>>>(W_w, wwb);

    k_bwd_mfma<<<dim3(8, 32, 3), 256, 0, stream>>>(
        h_tensor, last_idx, wcat2, bsum2, c0, yb_last);
    k_fc_last_mfma<<<dim3(2, 32, 3), 256, 0, stream>>>(hA, yb_last, fcb2, ys_last);
    k_wx_mfma<<<dim3(8, 32), 256, 0, stream>>>(x, wwb, W_b, WxBuf);

    k_final<<<N_SEQ, 256, 0, stream>>>(WxBuf, ys0, ys_last, c_tensor, indice, out);
}

// Round 2
// 1297.809 us; speedup vs baseline: 1.1595x; 1.0708x over previous
//
#include <hip/hip_runtime.h>
#include <math.h>

#define N_SEQ 4096
#define KCH   16
#define DM    256
#define G4    1024
// padded-LDS pitch for the legacy post-round kernels
#define LP    40
#define EP    68   // epilogue scratch pitch in floats

typedef __attribute__((ext_vector_type(8))) short bf8;
typedef __attribute__((ext_vector_type(4))) float f4;

__device__ __forceinline__ float fast_rcp(float x) { return __builtin_amdgcn_rcpf(x); }
__device__ __forceinline__ float sigf(float x)   { return fast_rcp(1.f + __expf(-x)); }
__device__ __forceinline__ float tanh_f(float x) { return 1.f - 2.f * fast_rcp(1.f + __expf(2.f * x)); }

__device__ __forceinline__ float bf2f(unsigned short u) {
    return __uint_as_float(((unsigned)u) << 16);
}
__device__ __forceinline__ unsigned short f2bf(float f) {
    unsigned u = __float_as_uint(f);
    unsigned r = (u + 0x7fffu + ((u >> 16) & 1u)) >> 16;   // RNE
    return (unsigned short)r;
}
__device__ __forceinline__ unsigned pack2(float a, float b) {
    return (unsigned)f2bf(a) | ((unsigned)f2bf(b) << 16);
}

// async global->LDS, 16B per lane; LDS dest = wave-uniform base + lane*16
#define GLDS(gp, lp) __builtin_amdgcn_global_load_lds( \
    (const __attribute__((address_space(1))) void*)(gp), \
    (__attribute__((address_space(3))) void*)(lp), 16, 0, 0)

// ===========================================================================
// Pipelined MFMA pass: acc[4][4] += A[128,K]@B[128,K]^T over NSEG segments of
// K=256 each, bf16, rows dense.  TRIPLE-buffered LDS tiles (3 x 16 KB = 48 KB)
// with a SINGLE barrier per K-step:
//   step t:  vmcnt(4)  -> own step-t loads landed (t+1's stay in flight)
//            s_barrier -> all waves' step-t tile complete; also proves every
//                         wave consumed its step t-1 ds_reads (lgkm-waited
//                         before its MFMAs), so buffer (t+2)%3 == (t-1)%3 is
//                         dead -> safe to overwrite
//            GLDS step t+2 into buffer (t+2)%3   (2-phase prefetch lead)
//            ds_read frags + 16 MFMA (setprio 1)
// No trailing lgkm barrier needed: issue-after-barrier removes the WAR hazard.
// Layout identical to the proven pass_glk: XOR chunk swizzle on the global
// source (jl) and on the fragment reads (jq); LDS itself linear.
// SM must hold 3*8192 shorts = 49,152 B.
// ===========================================================================
template<int NSEG, int LDB>
__device__ __forceinline__ void pass_pipe(
    const unsigned short* const (&segA)[NSEG],
    const unsigned short* const (&segB)[NSEG],
    unsigned short* SM,
    f4 (&acc)[4][4], int wave, int wm, int wn, int jq, int fr)
{
    constexpr int NS = NSEG * 8;

    // prologue: issue steps 0 and 1 into buffers 0 and 1
    {
        const unsigned short* A0 = segA[0];
        const unsigned short* B0 = segB[0];
        unsigned short* a = SM + wave * 1024;
        unsigned short* b = SM + 4096 + wave * 1024;
        GLDS(A0, a);            GLDS(A0 + 16 * DM, a + 512);
        GLDS(B0, b);            GLDS(B0 + 16 * LDB, b + 512);
        const unsigned short* A1 = segA[0] + 32;
        const unsigned short* B1 = segB[0] + 32;
        a = SM + 8192 + wave * 1024;
        b = SM + 8192 + 4096 + wave * 1024;
        GLDS(A1, a);            GLDS(A1 + 16 * DM, a + 512);
        GLDS(B1, b);            GLDS(B1 + 16 * LDB, b + 512);
    }
#pragma unroll
    for (int t = 0; t < NS; ++t) {
        if (t < NS - 1)
            asm volatile("s_waitcnt vmcnt(4)" ::: "memory");
        else
            asm volatile("s_waitcnt vmcnt(0)" ::: "memory");
        __builtin_amdgcn_s_barrier();

        if (t + 2 < NS) {
            const int tn = t + 2;
            const unsigned short* A_ = segA[tn >> 3] + (tn & 7) * 32;
            const unsigned short* B_ = segB[tn >> 3] + (tn & 7) * 32;
            unsigned short* a = SM + (tn % 3) * 8192 + wave * 1024;
            unsigned short* b = a + 4096;
            GLDS(A_, a);        GLDS(A_ + 16 * DM, a + 512);
            GLDS(B_, b);        GLDS(B_ + 16 * LDB, b + 512);
        }

        const unsigned short* Ab = SM + (t % 3) * 8192;
        const unsigned short* Bb = Ab + 4096;
        bf8 af[4], bb[4];
#pragma unroll
        for (int i = 0; i < 4; ++i)
            af[i] = *(const bf8*)(Ab + (wm + i * 16 + fr) * 32 + jq);
#pragma unroll
        for (int j = 0; j < 4; ++j)
            bb[j] = *(const bf8*)(Bb + (wn + j * 16 + fr) * 32 + jq);

        __builtin_amdgcn_s_setprio(1);
#pragma unroll
        for (int i = 0; i < 4; ++i)
#pragma unroll
            for (int j = 0; j < 4; ++j)
                acc[i][j] = __builtin_amdgcn_mfma_f32_16x16x32_bf16(
                    af[i], bb[j], acc[i][j], 0, 0, 0);
        __builtin_amdgcn_s_setprio(0);
    }
}

// ===========================================================================
// Legacy padded-LDS passes (post-round one-shot kernels; proven correct)
// ===========================================================================
template<int KLEN>
__device__ __forceinline__ void pass_bf(
    const unsigned short* __restrict__ aRow,
    const unsigned short* __restrict__ bRow,
    unsigned short* Asm, unsigned short* Bsm, f4 (&acc)[4][4])
{
    const int tid  = threadIdx.x;
    const int kh   = (tid & 1) * 16;
    const int srow = tid >> 1;
    const int lane = tid & 63, wave = tid >> 6;
    const int wm = (wave >> 1) * 64, wn = (wave & 1) * 64;
    const int fr = lane & 15, fk = (lane >> 4) * 8;
    unsigned short* da = Asm + srow * LP + kh;
    unsigned short* db = Bsm + srow * LP + kh;

    for (int k0 = 0; k0 < KLEN; k0 += 32) {
        __syncthreads();
        *(int4*)(da)     = *(const int4*)(aRow + k0 + kh);
        *(int4*)(da + 8) = *(const int4*)(aRow + k0 + kh + 8);
        *(int4*)(db)     = *(const int4*)(bRow + k0 + kh);
        *(int4*)(db + 8) = *(const int4*)(bRow + k0 + kh + 8);
        __syncthreads();
        bf8 af[4], bb[4];
#pragma unroll
        for (int i = 0; i < 4; ++i)
            af[i] = *(const bf8*)(Asm + (wm + i * 16 + fr) * LP + fk);
#pragma unroll
        for (int j = 0; j < 4; ++j)
            bb[j] = *(const bf8*)(Bsm + (wn + j * 16 + fr) * LP + fk);
#pragma unroll
        for (int i = 0; i < 4; ++i)
#pragma unroll
            for (int j = 0; j < 4; ++j)
                acc[i][j] = __builtin_amdgcn_mfma_f32_16x16x32_bf16(
                    af[i], bb[j], acc[i][j], 0, 0, 0);
    }
}

template<int KLEN>
__device__ __forceinline__ void pass_f32(
    const float* __restrict__ aRow,
    const unsigned short* __restrict__ bRow,
    unsigned short* Asm, unsigned short* Bsm, f4 (&acc)[4][4])
{
    const int tid  = threadIdx.x;
    const int kh   = (tid & 1) * 16;
    const int srow = tid >> 1;
    const int lane = tid & 63, wave = tid >> 6;
    const int wm = (wave >> 1) * 64, wn = (wave & 1) * 64;
    const int fr = lane & 15, fk = (lane >> 4) * 8;
    unsigned short* da = Asm + srow * LP + kh;
    unsigned short* db = Bsm + srow * LP + kh;

    for (int k0 = 0; k0 < KLEN; k0 += 32) {
        __syncthreads();
        {
            const float* s = aRow + k0 + kh;
            float4 v0 = *(const float4*)(s);
            float4 v1 = *(const float4*)(s + 4);
            float4 v2 = *(const float4*)(s + 8);
            float4 v3 = *(const float4*)(s + 12);
            *(int4*)(da)     = make_int4(pack2(v0.x, v0.y), pack2(v0.z, v0.w),
                                         pack2(v1.x, v1.y), pack2(v1.z, v1.w));
            *(int4*)(da + 8) = make_int4(pack2(v2.x, v2.y), pack2(v2.z, v2.w),
                                         pack2(v3.x, v3.y), pack2(v3.z, v3.w));
        }
        *(int4*)(db)     = *(const int4*)(bRow + k0 + kh);
        *(int4*)(db + 8) = *(const int4*)(bRow + k0 + kh + 8);
        __syncthreads();
        bf8 af[4], bb[4];
#pragma unroll
        for (int i = 0; i < 4; ++i)
            af[i] = *(const bf8*)(Asm + (wm + i * 16 + fr) * LP + fk);
#pragma unroll
        for (int j = 0; j < 4; ++j)
            bb[j] = *(const bf8*)(Bsm + (wn + j * 16 + fr) * LP + fk);
#pragma unroll
        for (int i = 0; i < 4; ++i)
#pragma unroll
            for (int j = 0; j < 4; ++j)
                acc[i][j] = __builtin_amdgcn_mfma_f32_16x16x32_bf16(
                    af[i], bb[j], acc[i][j], 0, 0, 0);
    }
}

// --------------------------- setup kernels ----------------------------------

__global__ __launch_bounds__(256) void k_lastidx(
    const int* __restrict__ indice, int* __restrict__ last_idx)
{
    const int n = blockIdx.x * 256 + threadIdx.x;
    if (n >= N_SEQ) return;
    int len = 0;
#pragma unroll
    for (int k = 0; k < KCH; ++k) len += (indice[n * KCH + k] != -1);
    last_idx[n] = indice[n * KCH + (len - 1)];
}

__global__ __launch_bounds__(1024) void k_hh0_bsum2(
    const float* __restrict__ bih, const float* __restrict__ bhh,
    const float* __restrict__ h0, const float* __restrict__ Whh,
    float* __restrict__ bsum2)
{
    const int jz = blockIdx.x, j = jz + 1;
    const int g = threadIdx.x;
    const int jd = j * 2 + 1;
    const float* wrow = Whh + ((size_t)jd * G4 + g) * DM;
    float s = bih[jd * G4 + g] + bhh[jd * G4 + g];
    for (int h = 0; h < DM; ++h) s = fmaf(h0[j * DM + h], wrow[h], s);
    const int c = (g & 255) * 4 + (g >> 8);
    bsum2[jz * G4 + c] = s;
}

__global__ __launch_bounds__(256) void k_init_states(
    const float* __restrict__ h0, const float* __restrict__ c0,
    unsigned short* __restrict__ hA, float* __restrict__ c_state)
{
    const int row = blockIdx.x;
    const int s = row >> 12;
    const int tree = (s < 4) ? s : 0;
    const int d = threadIdx.x;
    hA[(size_t)row * DM + d]      = f2bf(h0[tree * DM + d]);
    c_state[(size_t)row * DM + d] = c0[tree * DM + d];
}

__global__ __launch_bounds__(256) void k_zero4(float4* __restrict__ p)
{
    p[(size_t)blockIdx.x * 256 + threadIdx.x] = make_float4(0.f, 0.f, 0.f, 0.f);
}

__global__ __launch_bounds__(256) void k_prep_wcat(
    const float* __restrict__ Wih, const float* __restrict__ Whh,
    const float* __restrict__ bih, const float* __restrict__ bhh,
    unsigned short* __restrict__ wcat, float* __restrict__ bsumr)
{
    const int c = blockIdx.x, s = blockIdx.y;
    const int wsel = (s < 4) ? s * 2 : 1;
    const int d = c >> 2, g = c & 3;
    const size_t srcrow = ((size_t)wsel * G4 + g * DM + d) * DM;
    unsigned short* dst = wcat + ((size_t)s * G4 + c) * 512;
    const int t = threadIdx.x;
    dst[t]       = f2bf(Wih[srcrow + t]);
    dst[256 + t] = f2bf(Whh[srcrow + t]);
    if (t == 0)
        bsumr[s * G4 + c] = bih[wsel * G4 + g * DM + d] + bhh[wsel * G4 + g * DM + d];
}

__global__ __launch_bounds__(256) void k_prep_wcat2(
    const float* __restrict__ Wih, unsigned short* __restrict__ wcat2)
{
    const int c = blockIdx.x, jz = blockIdx.y, j = jz + 1;
    const int d = c >> 2, g = c & 3;
    const size_t srcrow = ((size_t)(j * 2 + 1) * G4 + g * DM + d) * DM;
    wcat2[((size_t)jz * G4 + c) * 256 + threadIdx.x] = f2bf(Wih[srcrow + threadIdx.x]);
}

__global__ __launch_bounds__(256) void k_prep_fcb(
    const float* __restrict__ fc, unsigned short* __restrict__ fcb)
{
    const int dout = blockIdx.x, z = blockIdx.y, t = threadIdx.x;
    fcb[((size_t)z * DM + dout) * DM + t] = f2bf(fc[(size_t)dout * 512 + z * DM + t]);
}

__global__ __launch_bounds__(256) void k_prep_fcb2(
    const float* __restrict__ fc, unsigned short* __restrict__ fcb2)
{
    const int dout = blockIdx.x, jz = blockIdx.y, j = jz + 1, t = threadIdx.x;
    const float* src = fc + ((size_t)j * DM + dout) * 512;
    unsigned short* dst = fcb2 + ((size_t)jz * DM + dout) * 512;
    dst[t]       = f2bf(src[t]);
    dst[t + 256] = f2bf(src[t + 256]);
}

__global__ __launch_bounds__(256) void k_prep_wwb(
    const float* __restrict__ W_w, unsigned short* __restrict__ wwb)
{
    const size_t i = (size_t)blockIdx.x * 256 + threadIdx.x;
    wwb[i] = f2bf(W_w[i]);
}

__device__ __forceinline__ void gather_slice(
    const float* __restrict__ h_tensor, const int* __restrict__ indice,
    unsigned short* __restrict__ xbuf, int zz, int kk, int blk)
{
    const int row = blk * 64 + (threadIdx.x >> 2);
    const int cb  = (threadIdx.x & 3) * 64;
    int idx = indice[row * KCH + kk]; if (idx < 0) idx = 0;
    const float* src = h_tensor + (size_t)idx * DM + cb;
    unsigned short* dst = xbuf + ((size_t)zz * N_SEQ + row) * DM + cb;
#pragma unroll
    for (int c = 0; c < 64; c += 4) {
        float4 v = *(const float4*)(src + c);
        *(uint2*)(dst + c) = make_uint2(pack2(v.x, v.y), pack2(v.z, v.w));
    }
}

__global__ __launch_bounds__(256) void k_gather_x0(
    const float* __restrict__ h_tensor, const int* __restrict__ indice,
    unsigned short* __restrict__ xbuf)
{
    const int slice = blockIdx.x >> 6, blk = blockIdx.x & 63;
    gather_slice(h_tensor, indice, xbuf, slice, slice ? (KCH - 1) : 0, blk);
}

// --------------------------- merged scan round ------------------------------
// grid (8, 32, 6):
//   bz<5 : scan for stream s=bz (XCD-swizzled: bn=by&7, bm=(by>>3)*8+bx so all
//          8 bn-siblings of one (bm,s) share id%8 -> same XCD -> A L2-local)
//   bz=5 : id5<128 -> acc_fc for round r-1 (y ping-pong);
//          id5>=128 -> gather xbuf slices for round r+1 (x ping-pong)
__global__ __launch_bounds__(256) void k_scan_merged(
    const unsigned short* __restrict__ xb_cur, unsigned short* __restrict__ xb_nxt,
    const unsigned short* __restrict__ yb_prev, unsigned short* __restrict__ yb_cur,
    const int* __restrict__ indice, const float* __restrict__ h_tensor,
    const unsigned short* __restrict__ h_in, unsigned short* __restrict__ h_out,
    float* __restrict__ c_state,
    const unsigned short* __restrict__ wcat, const float* __restrict__ bsumr,
    const unsigned short* __restrict__ fcb, unsigned short* __restrict__ ys0,
    int r)
{
    __shared__ __align__(16) unsigned short SMEM[24576];   // 49,152 B (3 bufs)

    const int tid  = threadIdx.x;
    const int lane = tid & 63, wave = tid >> 6;
    const int wm = (wave >> 1) * 64, wn = (wave & 1) * 64;
    const int fr = lane & 15;
    const int jq = ((lane >> 4) ^ ((fr >> 1) & 3)) * 8;        // frag-read swizzle
    const int lr = wave * 32 + (lane >> 2);                    // staging row
    const int jl = ((lane & 3) ^ ((lane >> 3) & 3)) * 8;       // staging swizzle

    const int bz = blockIdx.z;

    if (bz == 5) {
        const int id5 = blockIdx.x + 8 * blockIdx.y;
        if (id5 >= 128) {                 // gather role: xbuf for round r+1
            const int rr = r + 1;
            if (rr >= KCH) return;
            const int g = id5 - 128;
            const int zz = g >> 6;
            gather_slice(h_tensor, indice, xb_nxt, zz,
                         zz ? (KCH - 1 - rr) : rr, g & 63);
            return;
        }
        if (r == 0) return;               // acc role: fc-accumulate round r-1
        const int rp = r - 1;
        const int z = id5 >> 6;
        const int kslice = z ? (KCH - 1 - rp) : rp;
        const int row0 = (id5 & 31) * 128;
        const int c0 = ((id5 >> 5) & 1) * 128;

        const unsigned short* ay0 = yb_prev + ((size_t)z * N_SEQ + row0 + lr) * DM + jl;
        const unsigned short* bf0 = fcb + ((size_t)z * DM + c0 + lr) * DM + jl;

        f4 acc[4][4];
#pragma unroll
        for (int i = 0; i < 4; ++i)
#pragma unroll
            for (int j = 0; j < 4; ++j) acc[i][j] = (f4)(0.f);
        {
            const unsigned short* const segA[1] = { ay0 };
            const unsigned short* const segB[1] = { bf0 };
            pass_pipe<1, 256>(segA, segB, SMEM, acc, wave, wm, wn, jq, fr);
        }

#pragma unroll
        for (int i = 0; i < 4; ++i)
#pragma unroll
            for (int j = 0; j < 4; ++j) {
                const int col = c0 + wn + j * 16 + fr;
#pragma unroll
                for (int reg = 0; reg < 4; ++reg) {
                    const int rowg = row0 + wm + i * 16 + (lane >> 4) * 4 + reg;
                    const size_t ix = ((size_t)rowg * KCH + kslice) * DM + col;
                    ys0[ix] = f2bf(bf2f(ys0[ix]) + acc[i][j][reg]);
                }
            }
        return;
    }

    // ---- scan role ----
    const int s = bz;
    const int k = (s < 4) ? r : (KCH - 1 - r);
    const int z = (s < 4) ? 0 : 1;
    const int bn = blockIdx.y & 7;
    const int bm = (blockIdx.y >> 3) * 8 + blockIdx.x;
    const int row0 = bm * 128, c0 = bn * 128;

    const unsigned short* xz = xb_cur + (size_t)z * N_SEQ * DM;
    const unsigned short* hs_in = h_in + (size_t)s * N_SEQ * DM;
    const unsigned short* ax0 = xz + (size_t)(row0 + lr) * DM + jl;
    const unsigned short* ah0 = hs_in + (size_t)(row0 + lr) * DM + jl;
    const unsigned short* bw0 = wcat + ((size_t)s * G4 + c0 + lr) * 512 + jl;

    f4 acc[4][4];
#pragma unroll
    for (int i = 0; i < 4; ++i)
#pragma unroll
        for (int j = 0; j < 4; ++j) acc[i][j] = (f4)(0.f);

    {
        // one continuous 16-step pipeline across the x-pass and h-pass
        const unsigned short* const segA[2] = { ax0, ah0 };
        const unsigned short* const segB[2] = { bw0, bw0 + 256 };
        pass_pipe<2, 512>(segA, segB, SMEM, acc, wave, wm, wn, jq, fr);
    }

    // ---- fused LSTM epilogue ----
    // sc is WAVE-PRIVATE scratch: no cross-wave sharing, so inner-loop
    // __syncthreads() are replaced by per-wave lgkmcnt(0) waits.
    float* sc = (float*)SMEM + wave * (16 * EP);
    __syncthreads();   // SMEM handoff from MFMA tiles (cross-wave)
#pragma unroll
    for (int i = 0; i < 4; ++i) {
#pragma unroll
        for (int j = 0; j < 4; ++j) {
            const int colL = j * 16 + fr;
            const int rbase = (lane >> 4) * 4;
#pragma unroll
            for (int reg = 0; reg < 4; ++reg)
                sc[(rbase + reg) * EP + colL] = acc[i][j][reg];
        }
        asm volatile("s_waitcnt lgkmcnt(0)" ::: "memory");
        __builtin_amdgcn_sched_barrier(0);
        const int rowg = row0 + wm + i * 16 + fr;
        const bool m = (indice[rowg * KCH + k] != -1);
#pragma unroll
        for (int q = 0; q < 4; ++q) {
            const int dL = (lane >> 4) + q * 4;
            const f4 gv = *(const f4*)(sc + fr * EP + dL * 4);
            const f4 bb = *(const f4*)(bsumr + s * G4 + c0 + wn + dL * 4);
            const int d = ((c0 + wn) >> 2) + dL;
            const float ii = sigf(gv.x + bb.x);
            const float ff = sigf(gv.y + bb.y);
            const float uu = tanh_f(gv.z + bb.z);
            const float oo = sigf(gv.w + bb.w);
            const size_t cix = ((size_t)s * N_SEQ + rowg) * DM + d;
            const float c_old = c_state[cix];
            const float cn = ff * c_old + ii * uu;
            const float cw = m ? cn : c_old;
            c_state[cix] = cw;
            const float hn = oo * tanh_f(cn);
            const unsigned short hv = m ? f2bf(hn) : hs_in[(size_t)rowg * DM + d];
            h_out[cix] = hv;
            if (s == 0)
                yb_cur[(size_t)rowg * DM + d] = m ? f2bf(hn) : (unsigned short)0;
            else if (s == 4)
                yb_cur[(size_t)(N_SEQ + rowg) * DM + d] = m ? f2bf(hn) : (unsigned short)0;
        }
        asm volatile("s_waitcnt lgkmcnt(0)" ::: "memory");
        __builtin_amdgcn_sched_barrier(0);
    }
}

// tail: acc_fc for r=15.  grid (2, 32, 2)
__global__ __launch_bounds__(256) void k_acc_tail(
    const unsigned short* __restrict__ ybuf, const unsigned short* __restrict__ fcb,
    unsigned short* __restrict__ ys0)
{
    __shared__ __align__(16) unsigned short SMEM[24576];
    const int tid = threadIdx.x;
    const int lane = tid & 63, wave = tid >> 6;
    const int wm = (wave >> 1) * 64, wn = (wave & 1) * 64;
    const int fr = lane & 15;
    const int jq = ((lane >> 4) ^ ((fr >> 1) & 3)) * 8;
    const int lr = wave * 32 + (lane >> 2);
    const int jl = ((lane & 3) ^ ((lane >> 3) & 3)) * 8;

    const int z = blockIdx.z;
    const int kslice = z ? 0 : (KCH - 1);
    const int row0 = blockIdx.y * 128, c0 = blockIdx.x * 128;

    const unsigned short* ay0 = ybuf + ((size_t)z * N_SEQ + row0 + lr) * DM + jl;
    const unsigned short* bf0 = fcb + ((size_t)z * DM + c0 + lr) * DM + jl;

    f4 acc[4][4];
#pragma unroll
    for (int i = 0; i < 4; ++i)
#pragma unroll
        for (int j = 0; j < 4; ++j) acc[i][j] = (f4)(0.f);
    {
        const unsigned short* const segA[1] = { ay0 };
        const unsigned short* const segB[1] = { bf0 };
        pass_pipe<1, 256>(segA, segB, SMEM, acc, wave, wm, wn, jq, fr);
    }

#pragma unroll
    for (int i = 0; i < 4; ++i)
#pragma unroll
        for (int j = 0; j < 4; ++j) {
            const int col = c0 + wn + j * 16 + fr;
#pragma unroll
            for (int reg = 0; reg < 4; ++reg) {
                const int rowg = row0 + wm + i * 16 + (lane >> 4) * 4 + reg;
                const size_t ix = ((size_t)rowg * KCH + kslice) * DM + col;
                ys0[ix] = f2bf(bf2f(ys0[ix]) + acc[i][j][reg]);
            }
        }
}

// --------------------------- post-round kernels -----------------------------

__global__ __launch_bounds__(256) void k_bwd_mfma(
    const float* __restrict__ h_tensor, const int* __restrict__ last_idx,
    const unsigned short* __restrict__ wcat2, const float* __restrict__ bsum2,
    const float* __restrict__ c0, unsigned short* __restrict__ yb_last)
{
    __shared__ __align__(16) unsigned short SMEM[2 * 128 * LP];
    const int jz = blockIdx.z, j = jz + 1;
    const int row0 = blockIdx.y * 128, c0t = blockIdx.x * 128;
    const int tid = threadIdx.x;
    const int srow = tid >> 1;

    const float* aF = h_tensor + (size_t)last_idx[row0 + srow] * DM;
    const unsigned short* bR = wcat2 + ((size_t)jz * G4 + c0t + srow) * 256;

    f4 acc[4][4];
#pragma unroll
    for (int i = 0; i < 4; ++i)
#pragma unroll
        for (int jj = 0; jj < 4; ++jj) acc[i][jj] = (f4)(0.f);

    pass_f32<256>(aF, bR, SMEM, SMEM + 128 * LP, acc);

    const int lane = tid & 63, wave = tid >> 6;
    const int wm = (wave >> 1) * 64, wn = (wave & 1) * 64;
    float* sc = (float*)SMEM + wave * (16 * EP);

    __syncthreads();
#pragma unroll
    for (int i = 0; i < 4; ++i) {
#pragma unroll
        for (int jj = 0; jj < 4; ++jj) {
            const int colL = jj * 16 + (lane & 15);
            const int rbase = (lane >> 4) * 4;
#pragma unroll
            for (int reg = 0; reg < 4; ++reg)
                sc[(rbase + reg) * EP + colL] = acc[i][jj][reg];
        }
        __syncthreads();
        const int rowg = row0 + wm + i * 16 + (lane & 15);
#pragma unroll
        for (int q = 0; q < 4; ++q) {
            const int dL = (lane >> 4) + q * 4;
            const f4 gv = *(const f4*)(sc + (lane & 15) * EP + dL * 4);
            const f4 bb = *(const f4*)(bsum2 + jz * G4 + c0t + wn + dL * 4);
            const int d = ((c0t + wn) >> 2) + dL;
            const float ii = sigf(gv.x + bb.x);
            const float ff = sigf(gv.y + bb.y);
            const float uu = tanh_f(gv.z + bb.z);
            const float oo = sigf(gv.w + bb.w);
            const float cn = ff * c0[j * DM + d] + ii * uu;
            yb_last[((size_t)jz * N_SEQ + rowg) * DM + d] = f2bf(oo * tanh_f(cn));
        }
        __syncthreads();
    }
}

__global__ __launch_bounds__(256) void k_wx_mfma(
    const float* __restrict__ x, const unsigned short* __restrict__ wwb,
    const float* __restrict__ W_b, unsigned short* __restrict__ Wx)
{
    __shared__ __align__(16) unsigned short SMEM[2 * 128 * LP];
    const int row0 = blockIdx.y * 128, c0 = blockIdx.x * 128;
    const int tid = threadIdx.x;
    const int srow = tid >> 1;

    const float* aF = x + (size_t)(row0 + srow) * DM;
    const unsigned short* bR = wwb + (size_t)(c0 + srow) * DM;

    f4 acc[4][4];
#pragma unroll
    for (int i = 0; i < 4; ++i)
#pragma unroll
        for (int j = 0; j < 4; ++j) acc[i][j] = (f4)(0.f);

    pass_f32<256>(aF, bR, SMEM, SMEM + 128 * LP, acc);

    const int lane = tid & 63, wave = tid >> 6;
    const int wm = (wave >> 1) * 64, wn = (wave & 1) * 64;
#pragma unroll
    for (int i = 0; i < 4; ++i)
#pragma unroll
        for (int j = 0; j < 4; ++j) {
            const int col = c0 + wn + j * 16 + (lane & 15);
            const float bv = W_b[col];
#pragma unroll
            for (int reg = 0; reg < 4; ++reg) {
                const int rowg = row0 + wm + i * 16 + (lane >> 4) * 4 + reg;
                Wx[(size_t)rowg * G4 + col] = f2bf(acc[i][j][reg] + bv);
            }
        }
}

__global__ __launch_bounds__(256) void k_fc_last_mfma(
    const unsigned short* __restrict__ h_final, const unsigned short* __restrict__ yb_last,
    const unsigned short* __restrict__ fcb2, unsigned short* __restrict__ ys_last)
{
    __shared__ __align__(16) unsigned short SMEM[2 * 128 * LP];
    const int jz = blockIdx.z;
    const int row0 = blockIdx.y * 128, c0 = blockIdx.x * 128;
    const int tid = threadIdx.x;
    const int srow = tid >> 1;

    const unsigned short* aH1 = h_final + ((size_t)(1 + jz) * N_SEQ + row0 + srow) * DM;
    const unsigned short* aH2 = yb_last + ((size_t)jz * N_SEQ + row0 + srow) * DM;
    const unsigned short* bR  = fcb2 + ((size_t)jz * DM + c0 + srow) * 512;

    f4 acc[4][4];
#pragma unroll
    for (int i = 0; i < 4; ++i)
#pragma unroll
        for (int j = 0; j < 4; ++j) acc[i][j] = (f4)(0.f);

    pass_bf<256>(aH1, bR, SMEM, SMEM + 128 * LP, acc);
    pass_bf<256>(aH2, bR + 256, SMEM, SMEM + 128 * LP, acc);

    const int lane = tid & 63, wave = tid >> 6;
    const int wm = (wave >> 1) * 64, wn = (wave & 1) * 64;
#pragma unroll
    for (int i = 0; i < 4; ++i)
#pragma unroll
        for (int j = 0; j < 4; ++j) {
            const int col = c0 + wn + j * 16 + (lane & 15);
#pragma unroll
            for (int reg = 0; reg < 4; ++reg) {
                const int rowg = row0 + wm + i * 16 + (lane >> 4) * 4 + reg;
                ys_last[((size_t)jz * N_SEQ + rowg) * DM + col] = f2bf(acc[i][j][reg]);
            }
        }
}

__global__ __launch_bounds__(256) void k_final(
    const unsigned short* __restrict__ Wx, const unsigned short* __restrict__ ys0,
    const unsigned short* __restrict__ ys_last, const float* __restrict__ c_tensor,
    const int* __restrict__ indice, float* __restrict__ out)
{
    const int n = blockIdx.x, d = threadIdx.x;
    const float Wf = bf2f(Wx[(size_t)n * G4 + d]);
    const float Wi = bf2f(Wx[(size_t)n * G4 + DM + d]);
    const float Wu = bf2f(Wx[(size_t)n * G4 + 2 * DM + d]);
    const float Wo = bf2f(Wx[(size_t)n * G4 + 3 * DM + d]);
    float bf = 0.f;
#pragma unroll
    for (int k = 0; k < KCH; ++k) {
        const int id = indice[n * KCH + k];
        if (id >= 0)
            bf += sigf(Wf + bf2f(ys0[((size_t)n * KCH + k) * DM + d])) *
                  c_tensor[(size_t)id * DM + d];
    }
    const float bi = sigf(bf2f(ys_last[((size_t)0 * N_SEQ + n) * DM + d]) + Wi);
    const float bu = tanh_f(bf2f(ys_last[((size_t)1 * N_SEQ + n) * DM + d]) + Wu);
    const float bo = sigf(bf2f(ys_last[((size_t)2 * N_SEQ + n) * DM + d]) + Wo);
    const float nc = bi * bu + bf;
    const float nh = bo * tanh_f(nc);
    out[(size_t)n * DM + d] = nh;
    out[(size_t)N_SEQ * DM + (size_t)n * DM + d] = nc;
}

// --------------------------- launcher ---------------------------------------
extern "C" void kernel_launch(void* const* d_in, const int* in_sizes, int n_in,
                              void* d_out, int out_size, void* d_ws, size_t ws_size,
                              hipStream_t stream)
{
    const float* x        = (const float*)d_in[0];
    const float* h_tensor = (const float*)d_in[1];
    const float* c_tensor = (const float*)d_in[2];
    const int*   indice   = (const int*)d_in[3];
    const float* W_w      = (const float*)d_in[4];
    const float* W_b      = (const float*)d_in[5];
    const float* h0       = (const float*)d_in[6];
    const float* c0       = (const float*)d_in[7];
    const float* Wih      = (const float*)d_in[8];
    const float* Whh      = (const float*)d_in[9];
    const float* bih      = (const float*)d_in[10];
    const float* bhh      = (const float*)d_in[11];
    const float* fc       = (const float*)d_in[12];
    float* out = (float*)d_out;

    // ---- workspace layout; need = 97,816,576 B (< proven 100,728,832) ----
    char* base = (char*)d_ws;
    float*          c_state  = (float*)(base + 0);                   // 20,971,520
    int*            last_idx = (int*)  (base + 20971520);            //     16,384
    float*          bsumr    = (float*)(base + 20987904);            //     20,480
    unsigned short* hA       = (unsigned short*)(base + 21008384);   // 10,485,760
    unsigned short* hB       = (unsigned short*)(base + 31494144);   // 10,485,760
    unsigned short* ys0      = (unsigned short*)(base + 41979904);   // 33,554,432
    unsigned short* ybufA    = (unsigned short*)(base + 75534336);   //  4,194,304
    unsigned short* ybufB    = (unsigned short*)(base + 79728640);   //  4,194,304
    unsigned short* xbufA    = (unsigned short*)(base + 83922944);   //  4,194,304
    unsigned short* fcb      = (unsigned short*)(base + 88117248);   //    262,144
    unsigned short* postbuf  = (unsigned short*)(base + 88379392);   //  4,194,304
    unsigned short* wcat     = (unsigned short*)(base + 92573696);   //  5,242,880
    const size_t need = 97816576;
    if (ws_size < need) return;   // diagnostic: zero-output absmax fail

    // aliases (disjoint lifetimes):
    unsigned short* xbufB   = postbuf;               // rounds only
    unsigned short* wcat2   = postbuf;               // post (1,572,864 B)
    unsigned short* fcb2    = postbuf + 786432;      // post (786,432 B)
    unsigned short* wwb     = postbuf + 1179648;     // post (524,288 B)
    float*          bsum2   = (float*)(postbuf + 1441792);  // post (12,288 B)
    unsigned short* yb_last = ybufA;                 // post (6.29 MB spans ybufA+B)
    unsigned short* ys_last = hB;                    // post (final h in hA)
    unsigned short* WxBuf   = hA;                    // post-fc_last (hA dead)

    k_lastidx<<<16, 256, 0, stream>>>(indice, last_idx);
    k_init_states<<<5 * N_SEQ, 256, 0, stream>>>(h0, c0, hA, c_state);
    k_zero4<<<8192, 256, 0, stream>>>((float4*)ys0);
    k_prep_wcat<<<dim3(G4, 5), 256, 0, stream>>>(Wih, Whh, bih, bhh, wcat, bsumr);
    k_prep_fcb<<<dim3(DM, 2), 256, 0, stream>>>(fc, fcb);
    k_gather_x0<<<128, 256, 0, stream>>>(h_tensor, indice, xbufA);

    for (int r = 0; r < KCH; ++r) {
        const unsigned short* xb_cur = (r & 1) ? xbufB : xbufA;
        unsigned short* xb_nxt       = (r & 1) ? xbufA : xbufB;
        const unsigned short* yb_prev = (r & 1) ? ybufA : ybufB;
        unsigned short* yb_cur        = (r & 1) ? ybufB : ybufA;
        const unsigned short* h_in = (r & 1) ? hB : hA;
        unsigned short* h_out      = (r & 1) ? hA : hB;
        k_scan_merged<<<dim3(8, 32, 6), 256, 0, stream>>>(
            xb_cur, xb_nxt, yb_prev, yb_cur, indice, h_tensor,
            h_in, h_out, c_state, wcat, bsumr, fcb, ys0, r);
    }
    // r=15 odd -> final h in hA; y_cur(r=15) in ybufB.

    k_acc_tail<<<dim3(2, 32, 2), 256, 0, stream>>>(ybufB, fcb, ys0);

    // post preps into postbuf (xbufB dead)
    k_prep_wcat2<<<dim3(G4, 3), 256, 0, stream>>>(Wih, wcat2);
    k_hh0_bsum2<<<3, 1024, 0, stream>>>(bih, bhh, h0, Whh, bsum2);
    k_prep_fcb2<<<dim3(DM, 3), 256, 0, stream>>>(fc, fcb2);
    k_prep_wwb<<<1024, 256, 0, stream>>>(W_w, wwb);

    k_bwd_mfma<<<dim3(8, 32, 3), 256, 0, stream>>>(
        h_tensor, last_idx, wcat2, bsum2, c0, yb_last);
    k_fc_last_mfma<<<dim3(2, 32, 3), 256, 0, stream>>>(hA, yb_last, fcb2, ys_last);
    k_wx_mfma<<<dim3(8, 32), 256, 0, stream>>>(x, wwb, W_b, WxBuf);

    k_final<<<N_SEQ, 256, 0, stream>>>(WxBuf, ys0, ys_last, c_tensor, indice, out);
}

// Round 3
// 1207.785 us; speedup vs baseline: 1.2459x; 1.0745x over previous
//
#include <hip/hip_runtime.h>
#include <math.h>

#define N_SEQ 4096
#define KCH   16
#define DM    256
#define G4    1024
// padded-LDS pitch for the legacy post-round kernels
#define LP    40
#define EP    68   // epilogue scratch pitch in floats

typedef __attribute__((ext_vector_type(8))) short bf8;
typedef __attribute__((ext_vector_type(4))) float f4;

__device__ __forceinline__ float fast_rcp(float x) { return __builtin_amdgcn_rcpf(x); }
__device__ __forceinline__ float sigf(float x)   { return fast_rcp(1.f + __expf(-x)); }
__device__ __forceinline__ float tanh_f(float x) { return 1.f - 2.f * fast_rcp(1.f + __expf(2.f * x)); }

__device__ __forceinline__ float bf2f(unsigned short u) {
    return __uint_as_float(((unsigned)u) << 16);
}
__device__ __forceinline__ unsigned short f2bf(float f) {
    unsigned u = __float_as_uint(f);
    unsigned r = (u + 0x7fffu + ((u >> 16) & 1u)) >> 16;   // RNE
    return (unsigned short)r;
}
__device__ __forceinline__ unsigned pack2(float a, float b) {
    return (unsigned)f2bf(a) | ((unsigned)f2bf(b) << 16);
}

// async global->LDS, 16B per lane; LDS dest = wave-uniform base + lane*16
#define GLDS(gp, lp) __builtin_amdgcn_global_load_lds( \
    (const __attribute__((address_space(1))) void*)(gp), \
    (__attribute__((address_space(3))) void*)(lp), 16, 0, 0)

#define VW(n) asm volatile("s_waitcnt vmcnt(" #n ")" ::: "memory")

// ===========================================================================
// Pipelined MFMA pass: acc[4][4] += A[128,K]@B[128,K]^T over NSEG segments of
// K=256 each, bf16, rows dense.  5 LDS tile buffers (5 x 16 KB = 80 KB) with
// a 4-step prefetch lead and a SINGLE barrier per K-step:
//   step t:  vmcnt(12) -> own step-t loads landed (t+1..t+3's in flight)
//            s_barrier -> all waves' step-t tile complete; also proves every
//                         wave consumed its step t-1 ds_reads (lgkm-waited
//                         before its MFMAs), so buffer (t+4)%5 == (t-1)%5 is
//                         dead -> safe to overwrite
//            GLDS step t+4 into buffer (t+4)%5   (4-phase ~800cy lead,
//                                                 covers HBM-miss latency)
//            ds_read frags + 16 MFMA (setprio 1)
// Safety requires lead L <= NB-1 (4 <= 4 OK).  Never vmcnt(0) mid-loop.
// Layout identical to the proven pass_glk: XOR chunk swizzle on the global
// source (jl) and on the fragment reads (jq); LDS itself linear.
// SM must hold 5*8192 shorts = 81,920 B.
// ===========================================================================
template<int NSEG, int LDB>
__device__ __forceinline__ void pass_pipe(
    const unsigned short* const (&segA)[NSEG],
    const unsigned short* const (&segB)[NSEG],
    unsigned short* SM,
    f4 (&acc)[4][4], int wave, int wm, int wn, int jq, int fr)
{
    constexpr int NS = NSEG * 8;
    constexpr int L  = 4;                       // prefetch lead (steps)
    constexpr int NP = (NS < L) ? NS : L;

    // prologue: issue steps 0..NP-1 into buffers 0..NP-1
#pragma unroll
    for (int p = 0; p < NP; ++p) {
        const unsigned short* A_ = segA[p >> 3] + (p & 7) * 32;
        const unsigned short* B_ = segB[p >> 3] + (p & 7) * 32;
        unsigned short* a = SM + (p % 5) * 8192 + wave * 1024;
        unsigned short* b = a + 4096;
        GLDS(A_, a);        GLDS(A_ + 16 * DM, a + 512);
        GLDS(B_, b);        GLDS(B_ + 16 * LDB, b + 512);
    }
#pragma unroll
    for (int t = 0; t < NS; ++t) {
        // wait only for step-t's 4 loads (in-order vmcnt retire)
        const int rem = NS - 1 - t;
        if (rem >= 3)      VW(12);
        else if (rem == 2) VW(8);
        else if (rem == 1) VW(4);
        else               VW(0);
        __builtin_amdgcn_s_barrier();          // all waves' step-t data landed

        if (t + L < NS) {
            const int tn = t + L;
            const unsigned short* A_ = segA[tn >> 3] + (tn & 7) * 32;
            const unsigned short* B_ = segB[tn >> 3] + (tn & 7) * 32;
            unsigned short* a = SM + (tn % 5) * 8192 + wave * 1024;
            unsigned short* b = a + 4096;
            GLDS(A_, a);    GLDS(A_ + 16 * DM, a + 512);
            GLDS(B_, b);    GLDS(B_ + 16 * LDB, b + 512);
        }

        const unsigned short* Ab = SM + (t % 5) * 8192;
        const unsigned short* Bb = Ab + 4096;
        bf8 af[4], bb[4];
#pragma unroll
        for (int i = 0; i < 4; ++i)
            af[i] = *(const bf8*)(Ab + (wm + i * 16 + fr) * 32 + jq);
#pragma unroll
        for (int j = 0; j < 4; ++j)
            bb[j] = *(const bf8*)(Bb + (wn + j * 16 + fr) * 32 + jq);

        __builtin_amdgcn_s_setprio(1);
#pragma unroll
        for (int i = 0; i < 4; ++i)
#pragma unroll
            for (int j = 0; j < 4; ++j)
                acc[i][j] = __builtin_amdgcn_mfma_f32_16x16x32_bf16(
                    af[i], bb[j], acc[i][j], 0, 0, 0);
        __builtin_amdgcn_s_setprio(0);
    }
}

// ===========================================================================
// Legacy padded-LDS passes (post-round one-shot kernels; proven correct)
// ===========================================================================
template<int KLEN>
__device__ __forceinline__ void pass_bf(
    const unsigned short* __restrict__ aRow,
    const unsigned short* __restrict__ bRow,
    unsigned short* Asm, unsigned short* Bsm, f4 (&acc)[4][4])
{
    const int tid  = threadIdx.x;
    const int kh   = (tid & 1) * 16;
    const int srow = tid >> 1;
    const int lane = tid & 63, wave = tid >> 6;
    const int wm = (wave >> 1) * 64, wn = (wave & 1) * 64;
    const int fr = lane & 15, fk = (lane >> 4) * 8;
    unsigned short* da = Asm + srow * LP + kh;
    unsigned short* db = Bsm + srow * LP + kh;

    for (int k0 = 0; k0 < KLEN; k0 += 32) {
        __syncthreads();
        *(int4*)(da)     = *(const int4*)(aRow + k0 + kh);
        *(int4*)(da + 8) = *(const int4*)(aRow + k0 + kh + 8);
        *(int4*)(db)     = *(const int4*)(bRow + k0 + kh);
        *(int4*)(db + 8) = *(const int4*)(bRow + k0 + kh + 8);
        __syncthreads();
        bf8 af[4], bb[4];
#pragma unroll
        for (int i = 0; i < 4; ++i)
            af[i] = *(const bf8*)(Asm + (wm + i * 16 + fr) * LP + fk);
#pragma unroll
        for (int j = 0; j < 4; ++j)
            bb[j] = *(const bf8*)(Bsm + (wn + j * 16 + fr) * LP + fk);
#pragma unroll
        for (int i = 0; i < 4; ++i)
#pragma unroll
            for (int j = 0; j < 4; ++j)
                acc[i][j] = __builtin_amdgcn_mfma_f32_16x16x32_bf16(
                    af[i], bb[j], acc[i][j], 0, 0, 0);
    }
}

template<int KLEN>
__device__ __forceinline__ void pass_f32(
    const float* __restrict__ aRow,
    const unsigned short* __restrict__ bRow,
    unsigned short* Asm, unsigned short* Bsm, f4 (&acc)[4][4])
{
    const int tid  = threadIdx.x;
    const int kh   = (tid & 1) * 16;
    const int srow = tid >> 1;
    const int lane = tid & 63, wave = tid >> 6;
    const int wm = (wave >> 1) * 64, wn = (wave & 1) * 64;
    const int fr = lane & 15, fk = (lane >> 4) * 8;
    unsigned short* da = Asm + srow * LP + kh;
    unsigned short* db = Bsm + srow * LP + kh;

    for (int k0 = 0; k0 < KLEN; k0 += 32) {
        __syncthreads();
        {
            const float* s = aRow + k0 + kh;
            float4 v0 = *(const float4*)(s);
            float4 v1 = *(const float4*)(s + 4);
            float4 v2 = *(const float4*)(s + 8);
            float4 v3 = *(const float4*)(s + 12);
            *(int4*)(da)     = make_int4(pack2(v0.x, v0.y), pack2(v0.z, v0.w),
                                         pack2(v1.x, v1.y), pack2(v1.z, v1.w));
            *(int4*)(da + 8) = make_int4(pack2(v2.x, v2.y), pack2(v2.z, v2.w),
                                         pack2(v3.x, v3.y), pack2(v3.z, v3.w));
        }
        *(int4*)(db)     = *(const int4*)(bRow + k0 + kh);
        *(int4*)(db + 8) = *(const int4*)(bRow + k0 + kh + 8);
        __syncthreads();
        bf8 af[4], bb[4];
#pragma unroll
        for (int i = 0; i < 4; ++i)
            af[i] = *(const bf8*)(Asm + (wm + i * 16 + fr) * LP + fk);
#pragma unroll
        for (int j = 0; j < 4; ++j)
            bb[j] = *(const bf8*)(Bsm + (wn + j * 16 + fr) * LP + fk);
#pragma unroll
        for (int i = 0; i < 4; ++i)
#pragma unroll
            for (int j = 0; j < 4; ++j)
                acc[i][j] = __builtin_amdgcn_mfma_f32_16x16x32_bf16(
                    af[i], bb[j], acc[i][j], 0, 0, 0);
    }
}

// --------------------------- setup kernels ----------------------------------

__global__ __launch_bounds__(256) void k_lastidx(
    const int* __restrict__ indice, int* __restrict__ last_idx)
{
    const int n = blockIdx.x * 256 + threadIdx.x;
    if (n >= N_SEQ) return;
    int len = 0;
#pragma unroll
    for (int k = 0; k < KCH; ++k) len += (indice[n * KCH + k] != -1);
    last_idx[n] = indice[n * KCH + (len - 1)];
}

__global__ __launch_bounds__(1024) void k_hh0_bsum2(
    const float* __restrict__ bih, const float* __restrict__ bhh,
    const float* __restrict__ h0, const float* __restrict__ Whh,
    float* __restrict__ bsum2)
{
    const int jz = blockIdx.x, j = jz + 1;
    const int g = threadIdx.x;
    const int jd = j * 2 + 1;
    const float* wrow = Whh + ((size_t)jd * G4 + g) * DM;
    float s = bih[jd * G4 + g] + bhh[jd * G4 + g];
    for (int h = 0; h < DM; ++h) s = fmaf(h0[j * DM + h], wrow[h], s);
    const int c = (g & 255) * 4 + (g >> 8);
    bsum2[jz * G4 + c] = s;
}

__global__ __launch_bounds__(256) void k_init_states(
    const float* __restrict__ h0, const float* __restrict__ c0,
    unsigned short* __restrict__ hA, float* __restrict__ c_state)
{
    const int row = blockIdx.x;
    const int s = row >> 12;
    const int tree = (s < 4) ? s : 0;
    const int d = threadIdx.x;
    hA[(size_t)row * DM + d]      = f2bf(h0[tree * DM + d]);
    c_state[(size_t)row * DM + d] = c0[tree * DM + d];
}

__global__ __launch_bounds__(256) void k_zero4(float4* __restrict__ p)
{
    p[(size_t)blockIdx.x * 256 + threadIdx.x] = make_float4(0.f, 0.f, 0.f, 0.f);
}

__global__ __launch_bounds__(256) void k_prep_wcat(
    const float* __restrict__ Wih, const float* __restrict__ Whh,
    const float* __restrict__ bih, const float* __restrict__ bhh,
    unsigned short* __restrict__ wcat, float* __restrict__ bsumr)
{
    const int c = blockIdx.x, s = blockIdx.y;
    const int wsel = (s < 4) ? s * 2 : 1;
    const int d = c >> 2, g = c & 3;
    const size_t srcrow = ((size_t)wsel * G4 + g * DM + d) * DM;
    unsigned short* dst = wcat + ((size_t)s * G4 + c) * 512;
    const int t = threadIdx.x;
    dst[t]       = f2bf(Wih[srcrow + t]);
    dst[256 + t] = f2bf(Whh[srcrow + t]);
    if (t == 0)
        bsumr[s * G4 + c] = bih[wsel * G4 + g * DM + d] + bhh[wsel * G4 + g * DM + d];
}

__global__ __launch_bounds__(256) void k_prep_wcat2(
    const float* __restrict__ Wih, unsigned short* __restrict__ wcat2)
{
    const int c = blockIdx.x, jz = blockIdx.y, j = jz + 1;
    const int d = c >> 2, g = c & 3;
    const size_t srcrow = ((size_t)(j * 2 + 1) * G4 + g * DM + d) * DM;
    wcat2[((size_t)jz * G4 + c) * 256 + threadIdx.x] = f2bf(Wih[srcrow + threadIdx.x]);
}

__global__ __launch_bounds__(256) void k_prep_fcb(
    const float* __restrict__ fc, unsigned short* __restrict__ fcb)
{
    const int dout = blockIdx.x, z = blockIdx.y, t = threadIdx.x;
    fcb[((size_t)z * DM + dout) * DM + t] = f2bf(fc[(size_t)dout * 512 + z * DM + t]);
}

__global__ __launch_bounds__(256) void k_prep_fcb2(
    const float* __restrict__ fc, unsigned short* __restrict__ fcb2)
{
    const int dout = blockIdx.x, jz = blockIdx.y, j = jz + 1, t = threadIdx.x;
    const float* src = fc + ((size_t)j * DM + dout) * 512;
    unsigned short* dst = fcb2 + ((size_t)jz * DM + dout) * 512;
    dst[t]       = f2bf(src[t]);
    dst[t + 256] = f2bf(src[t + 256]);
}

__global__ __launch_bounds__(256) void k_prep_wwb(
    const float* __restrict__ W_w, unsigned short* __restrict__ wwb)
{
    const size_t i = (size_t)blockIdx.x * 256 + threadIdx.x;
    wwb[i] = f2bf(W_w[i]);
}

__device__ __forceinline__ void gather_slice(
    const float* __restrict__ h_tensor, const int* __restrict__ indice,
    unsigned short* __restrict__ xbuf, int zz, int kk, int blk)
{
    const int row = blk * 64 + (threadIdx.x >> 2);
    const int cb  = (threadIdx.x & 3) * 64;
    int idx = indice[row * KCH + kk]; if (idx < 0) idx = 0;
    const float* src = h_tensor + (size_t)idx * DM + cb;
    unsigned short* dst = xbuf + ((size_t)zz * N_SEQ + row) * DM + cb;
#pragma unroll
    for (int c = 0; c < 64; c += 4) {
        float4 v = *(const float4*)(src + c);
        *(uint2*)(dst + c) = make_uint2(pack2(v.x, v.y), pack2(v.z, v.w));
    }
}

__global__ __launch_bounds__(256) void k_gather_x0(
    const float* __restrict__ h_tensor, const int* __restrict__ indice,
    unsigned short* __restrict__ xbuf)
{
    const int slice = blockIdx.x >> 6, blk = blockIdx.x & 63;
    gather_slice(h_tensor, indice, xbuf, slice, slice ? (KCH - 1) : 0, blk);
}

// --------------------------- merged scan round ------------------------------
// grid (8, 32, 6):
//   bz<5 : scan for stream s=bz (XCD-swizzled: bn=by&7, bm=(by>>3)*8+bx so all
//          8 bn-siblings of one (bm,s) share id%8 -> same XCD -> A L2-local)
//   bz=5 : id5<128 -> acc_fc for round r-1 (y ping-pong);
//          id5>=128 -> gather xbuf slices for round r+1 (x ping-pong)
__global__ __launch_bounds__(256) void k_scan_merged(
    const unsigned short* __restrict__ xb_cur, unsigned short* __restrict__ xb_nxt,
    const unsigned short* __restrict__ yb_prev, unsigned short* __restrict__ yb_cur,
    const int* __restrict__ indice, const float* __restrict__ h_tensor,
    const unsigned short* __restrict__ h_in, unsigned short* __restrict__ h_out,
    float* __restrict__ c_state,
    const unsigned short* __restrict__ wcat, const float* __restrict__ bsumr,
    const unsigned short* __restrict__ fcb, unsigned short* __restrict__ ys0,
    int r)
{
    __shared__ __align__(16) unsigned short SMEM[40960];   // 81,920 B (5 bufs)

    const int tid  = threadIdx.x;
    const int lane = tid & 63, wave = tid >> 6;
    const int wm = (wave >> 1) * 64, wn = (wave & 1) * 64;
    const int fr = lane & 15;
    const int jq = ((lane >> 4) ^ ((fr >> 1) & 3)) * 8;        // frag-read swizzle
    const int lr = wave * 32 + (lane >> 2);                    // staging row
    const int jl = ((lane & 3) ^ ((lane >> 3) & 3)) * 8;       // staging swizzle

    const int bz = blockIdx.z;

    if (bz == 5) {
        const int id5 = blockIdx.x + 8 * blockIdx.y;
        if (id5 >= 128) {                 // gather role: xbuf for round r+1
            const int rr = r + 1;
            if (rr >= KCH) return;
            const int g = id5 - 128;
            const int zz = g >> 6;
            gather_slice(h_tensor, indice, xb_nxt, zz,
                         zz ? (KCH - 1 - rr) : rr, g & 63);
            return;
        }
        if (r == 0) return;               // acc role: fc-accumulate round r-1
        const int rp = r - 1;
        const int z = id5 >> 6;
        const int kslice = z ? (KCH - 1 - rp) : rp;
        const int row0 = (id5 & 31) * 128;
        const int c0 = ((id5 >> 5) & 1) * 128;

        const unsigned short* ay0 = yb_prev + ((size_t)z * N_SEQ + row0 + lr) * DM + jl;
        const unsigned short* bf0 = fcb + ((size_t)z * DM + c0 + lr) * DM + jl;

        f4 acc[4][4];
#pragma unroll
        for (int i = 0; i < 4; ++i)
#pragma unroll
            for (int j = 0; j < 4; ++j) acc[i][j] = (f4)(0.f);
        {
            const unsigned short* const segA[1] = { ay0 };
            const unsigned short* const segB[1] = { bf0 };
            pass_pipe<1, 256>(segA, segB, SMEM, acc, wave, wm, wn, jq, fr);
        }

#pragma unroll
        for (int i = 0; i < 4; ++i)
#pragma unroll
            for (int j = 0; j < 4; ++j) {
                const int col = c0 + wn + j * 16 + fr;
#pragma unroll
                for (int reg = 0; reg < 4; ++reg) {
                    const int rowg = row0 + wm + i * 16 + (lane >> 4) * 4 + reg;
                    const size_t ix = ((size_t)rowg * KCH + kslice) * DM + col;
                    ys0[ix] = f2bf(bf2f(ys0[ix]) + acc[i][j][reg]);
                }
            }
        return;
    }

    // ---- scan role ----
    const int s = bz;
    const int k = (s < 4) ? r : (KCH - 1 - r);
    const int z = (s < 4) ? 0 : 1;
    const int bn = blockIdx.y & 7;
    const int bm = (blockIdx.y >> 3) * 8 + blockIdx.x;
    const int row0 = bm * 128, c0 = bn * 128;

    const unsigned short* xz = xb_cur + (size_t)z * N_SEQ * DM;
    const unsigned short* hs_in = h_in + (size_t)s * N_SEQ * DM;
    const unsigned short* ax0 = xz + (size_t)(row0 + lr) * DM + jl;
    const unsigned short* ah0 = hs_in + (size_t)(row0 + lr) * DM + jl;
    const unsigned short* bw0 = wcat + ((size_t)s * G4 + c0 + lr) * 512 + jl;

    f4 acc[4][4];
#pragma unroll
    for (int i = 0; i < 4; ++i)
#pragma unroll
        for (int j = 0; j < 4; ++j) acc[i][j] = (f4)(0.f);

    {
        // one continuous 16-step pipeline across the x-pass and h-pass
        const unsigned short* const segA[2] = { ax0, ah0 };
        const unsigned short* const segB[2] = { bw0, bw0 + 256 };
        pass_pipe<2, 512>(segA, segB, SMEM, acc, wave, wm, wn, jq, fr);
    }

    // ---- fused LSTM epilogue with masked-skip state traffic ----
    // c_state is updated IN-PLACE: unmasked rows are frozen -> no read/write.
    // h_out is ping-pong: unmasked rows need the freeze-copy only when the
    // PREVIOUS round was masked (else the 2-rounds-ago value is already the
    // frozen h(len-1)).  r==0 forces a full write (h_out uninitialized).
    float* sc = (float*)SMEM + wave * (16 * EP);
    __syncthreads();   // SMEM handoff from MFMA tiles (cross-wave)
    const int kprev = (s < 4) ? (k - 1) : (k + 1);
#pragma unroll
    for (int i = 0; i < 4; ++i) {
#pragma unroll
        for (int j = 0; j < 4; ++j) {
            const int colL = j * 16 + fr;
            const int rbase = (lane >> 4) * 4;
#pragma unroll
            for (int reg = 0; reg < 4; ++reg)
                sc[(rbase + reg) * EP + colL] = acc[i][j][reg];
        }
        asm volatile("s_waitcnt lgkmcnt(0)" ::: "memory");
        __builtin_amdgcn_sched_barrier(0);
        const int rowg = row0 + wm + i * 16 + fr;
        const bool m = (indice[rowg * KCH + k] != -1);
        const bool mpv = (r == 0) ? true : (indice[rowg * KCH + kprev] != -1);
#pragma unroll
        for (int q = 0; q < 4; ++q) {
            const int dL = (lane >> 4) + q * 4;
            const f4 gv = *(const f4*)(sc + fr * EP + dL * 4);
            const f4 bb = *(const f4*)(bsumr + s * G4 + c0 + wn + dL * 4);
            const int d = ((c0 + wn) >> 2) + dL;
            const size_t cix = ((size_t)s * N_SEQ + rowg) * DM + d;
            unsigned short hv = 0;
            if (m) {
                const float ii = sigf(gv.x + bb.x);
                const float ff = sigf(gv.y + bb.y);
                const float uu = tanh_f(gv.z + bb.z);
                const float oo = sigf(gv.w + bb.w);
                const float c_old = c_state[cix];
                const float cn = ff * c_old + ii * uu;
                c_state[cix] = cn;
                hv = f2bf(oo * tanh_f(cn));
                h_out[cix] = hv;
            } else if (mpv) {
                h_out[cix] = hs_in[(size_t)rowg * DM + d];
            }
            if (s == 0)
                yb_cur[(size_t)rowg * DM + d] = m ? hv : (unsigned short)0;
            else if (s == 4)
                yb_cur[(size_t)(N_SEQ + rowg) * DM + d] = m ? hv : (unsigned short)0;
        }
        asm volatile("s_waitcnt lgkmcnt(0)" ::: "memory");
        __builtin_amdgcn_sched_barrier(0);
    }
}

// tail: acc_fc for r=15.  grid (2, 32, 2)
__global__ __launch_bounds__(256) void k_acc_tail(
    const unsigned short* __restrict__ ybuf, const unsigned short* __restrict__ fcb,
    unsigned short* __restrict__ ys0)
{
    __shared__ __align__(16) unsigned short SMEM[40960];
    const int tid = threadIdx.x;
    const int lane = tid & 63, wave = tid >> 6;
    const int wm = (wave >> 1) * 64, wn = (wave & 1) * 64;
    const int fr = lane & 15;
    const int jq = ((lane >> 4) ^ ((fr >> 1) & 3)) * 8;
    const int lr = wave * 32 + (lane >> 2);
    const int jl = ((lane & 3) ^ ((lane >> 3) & 3)) * 8;

    const int z = blockIdx.z;
    const int kslice = z ? 0 : (KCH - 1);
    const int row0 = blockIdx.y * 128, c0 = blockIdx.x * 128;

    const unsigned short* ay0 = ybuf + ((size_t)z * N_SEQ + row0 + lr) * DM + jl;
    const unsigned short* bf0 = fcb + ((size_t)z * DM + c0 + lr) * DM + jl;

    f4 acc[4][4];
#pragma unroll
    for (int i = 0; i < 4; ++i)
#pragma unroll
        for (int j = 0; j < 4; ++j) acc[i][j] = (f4)(0.f);
    {
        const unsigned short* const segA[1] = { ay0 };
        const unsigned short* const segB[1] = { bf0 };
        pass_pipe<1, 256>(segA, segB, SMEM, acc, wave, wm, wn, jq, fr);
    }

#pragma unroll
    for (int i = 0; i < 4; ++i)
#pragma unroll
        for (int j = 0; j < 4; ++j) {
            const int col = c0 + wn + j * 16 + fr;
#pragma unroll
            for (int reg = 0; reg < 4; ++reg) {
                const int rowg = row0 + wm + i * 16 + (lane >> 4) * 4 + reg;
                const size_t ix = ((size_t)rowg * KCH + kslice) * DM + col;
                ys0[ix] = f2bf(bf2f(ys0[ix]) + acc[i][j][reg]);
            }
        }
}

// --------------------------- post-round kernels -----------------------------

__global__ __launch_bounds__(256) void k_bwd_mfma(
    const float* __restrict__ h_tensor, const int* __restrict__ last_idx,
    const unsigned short* __restrict__ wcat2, const float* __restrict__ bsum2,
    const float* __restrict__ c0, unsigned short* __restrict__ yb_last)
{
    __shared__ __align__(16) unsigned short SMEM[2 * 128 * LP];
    const int jz = blockIdx.z, j = jz + 1;
    const int row0 = blockIdx.y * 128, c0t = blockIdx.x * 128;
    const int tid = threadIdx.x;
    const int srow = tid >> 1;

    const float* aF = h_tensor + (size_t)last_idx[row0 + srow] * DM;
    const unsigned short* bR = wcat2 + ((size_t)jz * G4 + c0t + srow) * 256;

    f4 acc[4][4];
#pragma unroll
    for (int i = 0; i < 4; ++i)
#pragma unroll
        for (int jj = 0; jj < 4; ++jj) acc[i][jj] = (f4)(0.f);

    pass_f32<256>(aF, bR, SMEM, SMEM + 128 * LP, acc);

    const int lane = tid & 63, wave = tid >> 6;
    const int wm = (wave >> 1) * 64, wn = (wave & 1) * 64;
    float* sc = (float*)SMEM + wave * (16 * EP);

    __syncthreads();
#pragma unroll
    for (int i = 0; i < 4; ++i) {
#pragma unroll
        for (int jj = 0; jj < 4; ++jj) {
            const int colL = jj * 16 + (lane & 15);
            const int rbase = (lane >> 4) * 4;
#pragma unroll
            for (int reg = 0; reg < 4; ++reg)
                sc[(rbase + reg) * EP + colL] = acc[i][jj][reg];
        }
        __syncthreads();
        const int rowg = row0 + wm + i * 16 + (lane & 15);
#pragma unroll
        for (int q = 0; q < 4; ++q) {
            const int dL = (lane >> 4) + q * 4;
            const f4 gv = *(const f4*)(sc + (lane & 15) * EP + dL * 4);
            const f4 bb = *(const f4*)(bsum2 + jz * G4 + c0t + wn + dL * 4);
            const int d = ((c0t + wn) >> 2) + dL;
            const float ii = sigf(gv.x + bb.x);
            const float ff = sigf(gv.y + bb.y);
            const float uu = tanh_f(gv.z + bb.z);
            const float oo = sigf(gv.w + bb.w);
            const float cn = ff * c0[j * DM + d] + ii * uu;
            yb_last[((size_t)jz * N_SEQ + rowg) * DM + d] = f2bf(oo * tanh_f(cn));
        }
        __syncthreads();
    }
}

__global__ __launch_bounds__(256) void k_wx_mfma(
    const float* __restrict__ x, const unsigned short* __restrict__ wwb,
    const float* __restrict__ W_b, unsigned short* __restrict__ Wx)
{
    __shared__ __align__(16) unsigned short SMEM[2 * 128 * LP];
    const int row0 = blockIdx.y * 128, c0 = blockIdx.x * 128;
    const int tid = threadIdx.x;
    const int srow = tid >> 1;

    const float* aF = x + (size_t)(row0 + srow) * DM;
    const unsigned short* bR = wwb + (size_t)(c0 + srow) * DM;

    f4 acc[4][4];
#pragma unroll
    for (int i = 0; i < 4; ++i)
#pragma unroll
        for (int j = 0; j < 4; ++j) acc[i][j] = (f4)(0.f);

    pass_f32<256>(aF, bR, SMEM, SMEM + 128 * LP, acc);

    const int lane = tid & 63, wave = tid >> 6;
    const int wm = (wave >> 1) * 64, wn = (wave & 1) * 64;
#pragma unroll
    for (int i = 0; i < 4; ++i)
#pragma unroll
        for (int j = 0; j < 4; ++j) {
            const int col = c0 + wn + j * 16 + (lane & 15);
            const float bv = W_b[col];
#pragma unroll
            for (int reg = 0; reg < 4; ++reg) {
                const int rowg = row0 + wm + i * 16 + (lane >> 4) * 4 + reg;
                Wx[(size_t)rowg * G4 + col] = f2bf(acc[i][j][reg] + bv);
            }
        }
}

__global__ __launch_bounds__(256) void k_fc_last_mfma(
    const unsigned short* __restrict__ h_final, const unsigned short* __restrict__ yb_last,
    const unsigned short* __restrict__ fcb2, unsigned short* __restrict__ ys_last)
{
    __shared__ __align__(16) unsigned short SMEM[2 * 128 * LP];
    const int jz = blockIdx.z;
    const int row0 = blockIdx.y * 128, c0 = blockIdx.x * 128;
    const int tid = threadIdx.x;
    const int srow = tid >> 1;

    const unsigned short* aH1 = h_final + ((size_t)(1 + jz) * N_SEQ + row0 + srow) * DM;
    const unsigned short* aH2 = yb_last + ((size_t)jz * N_SEQ + row0 + srow) * DM;
    const unsigned short* bR  = fcb2 + ((size_t)jz * DM + c0 + srow) * 512;

    f4 acc[4][4];
#pragma unroll
    for (int i = 0; i < 4; ++i)
#pragma unroll
        for (int j = 0; j < 4; ++j) acc[i][j] = (f4)(0.f);

    pass_bf<256>(aH1, bR, SMEM, SMEM + 128 * LP, acc);
    pass_bf<256>(aH2, bR + 256, SMEM, SMEM + 128 * LP, acc);

    const int lane = tid & 63, wave = tid >> 6;
    const int wm = (wave >> 1) * 64, wn = (wave & 1) * 64;
#pragma unroll
    for (int i = 0; i < 4; ++i)
#pragma unroll
        for (int j = 0; j < 4; ++j) {
            const int col = c0 + wn + j * 16 + (lane & 15);
#pragma unroll
            for (int reg = 0; reg < 4; ++reg) {
                const int rowg = row0 + wm + i * 16 + (lane >> 4) * 4 + reg;
                ys_last[((size_t)jz * N_SEQ + rowg) * DM + col] = f2bf(acc[i][j][reg]);
            }
        }
}

__global__ __launch_bounds__(256) void k_final(
    const unsigned short* __restrict__ Wx, const unsigned short* __restrict__ ys0,
    const unsigned short* __restrict__ ys_last, const float* __restrict__ c_tensor,
    const int* __restrict__ indice, float* __restrict__ out)
{
    const int n = blockIdx.x, d = threadIdx.x;
    const float Wf = bf2f(Wx[(size_t)n * G4 + d]);
    const float Wi = bf2f(Wx[(size_t)n * G4 + DM + d]);
    const float Wu = bf2f(Wx[(size_t)n * G4 + 2 * DM + d]);
    const float Wo = bf2f(Wx[(size_t)n * G4 + 3 * DM + d]);
    float bf = 0.f;
#pragma unroll
    for (int k = 0; k < KCH; ++k) {
        const int id = indice[n * KCH + k];
        if (id >= 0)
            bf += sigf(Wf + bf2f(ys0[((size_t)n * KCH + k) * DM + d])) *
                  c_tensor[(size_t)id * DM + d];
    }
    const float bi = sigf(bf2f(ys_last[((size_t)0 * N_SEQ + n) * DM + d]) + Wi);
    const float bu = tanh_f(bf2f(ys_last[((size_t)1 * N_SEQ + n) * DM + d]) + Wu);
    const float bo = sigf(bf2f(ys_last[((size_t)2 * N_SEQ + n) * DM + d]) + Wo);
    const float nc = bi * bu + bf;
    const float nh = bo * tanh_f(nc);
    out[(size_t)n * DM + d] = nh;
    out[(size_t)N_SEQ * DM + (size_t)n * DM + d] = nc;
}

// --------------------------- launcher ---------------------------------------
extern "C" void kernel_launch(void* const* d_in, const int* in_sizes, int n_in,
                              void* d_out, int out_size, void* d_ws, size_t ws_size,
                              hipStream_t stream)
{
    const float* x        = (const float*)d_in[0];
    const float* h_tensor = (const float*)d_in[1];
    const float* c_tensor = (const float*)d_in[2];
    const int*   indice   = (const int*)d_in[3];
    const float* W_w      = (const float*)d_in[4];
    const float* W_b      = (const float*)d_in[5];
    const float* h0       = (const float*)d_in[6];
    const float* c0       = (const float*)d_in[7];
    const float* Wih      = (const float*)d_in[8];
    const float* Whh      = (const float*)d_in[9];
    const float* bih      = (const float*)d_in[10];
    const float* bhh      = (const float*)d_in[11];
    const float* fc       = (const float*)d_in[12];
    float* out = (float*)d_out;

    // ---- workspace layout; need = 97,816,576 B (< proven 100,728,832) ----
    char* base = (char*)d_ws;
    float*          c_state  = (float*)(base + 0);                   // 20,971,520
    int*            last_idx = (int*)  (base + 20971520);            //     16,384
    float*          bsumr    = (float*)(base + 20987904);            //     20,480
    unsigned short* hA       = (unsigned short*)(base + 21008384);   // 10,485,760
    unsigned short* hB       = (unsigned short*)(base + 31494144);   // 10,485,760
    unsigned short* ys0      = (unsigned short*)(base + 41979904);   // 33,554,432
    unsigned short* ybufA    = (unsigned short*)(base + 75534336);   //  4,194,304
    unsigned short* ybufB    = (unsigned short*)(base + 79728640);   //  4,194,304
    unsigned short* xbufA    = (unsigned short*)(base + 83922944);   //  4,194,304
    unsigned short* fcb      = (unsigned short*)(base + 88117248);   //    262,144
    unsigned short* postbuf  = (unsigned short*)(base + 88379392);   //  4,194,304
    unsigned short* wcat     = (unsigned short*)(base + 92573696);   //  5,242,880
    const size_t need = 97816576;
    if (ws_size < need) return;   // diagnostic: zero-output absmax fail

    // aliases (disjoint lifetimes):
    unsigned short* xbufB   = postbuf;               // rounds only
    unsigned short* wcat2   = postbuf;               // post (1,572,864 B)
    unsigned short* fcb2    = postbuf + 786432;      // post (786,432 B)
    unsigned short* wwb     = postbuf + 1179648;     // post (524,288 B)
    float*          bsum2   = (float*)(postbuf + 1441792);  // post (12,288 B)
    unsigned short* yb_last = ybufA;                 // post (6.29 MB spans ybufA+B)
    unsigned short* ys_last = hB;                    // post (final h in hA)
    unsigned short* WxBuf   = hA;                    // post-fc_last (hA dead)

    k_lastidx<<<16, 256, 0, stream>>>(indice, last_idx);
    k_init_states<<<5 * N_SEQ, 256, 0, stream>>>(h0, c0, hA, c_state);
    k_zero4<<<8192, 256, 0, stream>>>((float4*)ys0);
    k_prep_wcat<<<dim3(G4, 5), 256, 0, stream>>>(Wih, Whh, bih, bhh, wcat, bsumr);
    k_prep_fcb<<<dim3(DM, 2), 256, 0, stream>>>(fc, fcb);
    k_gather_x0<<<128, 256, 0, stream>>>(h_tensor, indice, xbufA);

    for (int r = 0; r < KCH; ++r) {
        const unsigned short* xb_cur = (r & 1) ? xbufB : xbufA;
        unsigned short* xb_nxt       = (r & 1) ? xbufA : xbufB;
        const unsigned short* yb_prev = (r & 1) ? ybufA : ybufB;
        unsigned short* yb_cur        = (r & 1) ? ybufB : ybufA;
        const unsigned short* h_in = (r & 1) ? hB : hA;
        unsigned short* h_out      = (r & 1) ? hA : hB;
        k_scan_merged<<<dim3(8, 32, 6), 256, 0, stream>>>(
            xb_cur, xb_nxt, yb_prev, yb_cur, indice, h_tensor,
            h_in, h_out, c_state, wcat, bsumr, fcb, ys0, r);
    }
    // r=15 odd -> final h in hA; y_cur(r=15) in ybufB.

    k_acc_tail<<<dim3(2, 32, 2), 256, 0, stream>>>(ybufB, fcb, ys0);

    // post preps into postbuf (xbufB dead)
    k_prep_wcat2<<<dim3(G4, 3), 256, 0, stream>>>(Wih, wcat2);
    k_hh0_bsum2<<<3, 1024, 0, stream>>>(bih, bhh, h0, Whh, bsum2);
    k_prep_fcb2<<<dim3(DM, 3), 256, 0, stream>>>(fc, fcb2);
    k_prep_wwb<<<1024, 256, 0, stream>>>(W_w, wwb);

    k_bwd_mfma<<<dim3(8, 32, 3), 256, 0, stream>>>(
        h_tensor, last_idx, wcat2, bsum2, c0, yb_last);
    k_fc_last_mfma<<<dim3(2, 32, 3), 256, 0, stream>>>(hA, yb_last, fcb2, ys_last);
    k_wx_mfma<<<dim3(8, 32), 256, 0, stream>>>(x, wwb, W_b, WxBuf);

    k_final<<<N_SEQ, 256, 0, stream>>>(WxBuf, ys0, ys_last, c_tensor, indice, out);
}